// Round 5
// baseline (690.984 us; speedup 1.0000x reference)
//
#include <hip/hip_runtime.h>
#include <hip/hip_bf16.h>
#include <cstddef>

// ---------------------------------------------------------------------------
// Constants for this problem: B=4, L=2048, D=1024
// ---------------------------------------------------------------------------
#define BB 4
#define LL 2048
#define DD 1024
#define MM (BB*LL)          // 8192 tokens
#define KF_STRIDE 2056      // complex elements per Kf row (>= 2049, 16B-aligned)

// LDS bank swizzle for float2 arrays: makes all Stockham read/write streams
// uniform across the 16 bank-pairs. Modifies bits 2-3 only (stays in range).
#define SWZ(a) ((a) ^ (((a) >> 4) & 12))

typedef __bf16 bf16_t;
typedef __attribute__((ext_vector_type(8))) __bf16 bf16x8;
typedef __attribute__((ext_vector_type(4))) __bf16 bf16x4;
typedef __attribute__((ext_vector_type(4))) float f32x4;

// async global->LDS, 16 bytes per lane (global_load_lds_dwordx4)
#define GLD_LDS16(gp, lp) __builtin_amdgcn_global_load_lds(                 \
    (const __attribute__((address_space(1))) unsigned int*)(gp),            \
    (__attribute__((address_space(3))) unsigned int*)(lp), 16, 0, 0)

__device__ __forceinline__ float gelu_tanh(float x) {
    const float c = 0.7978845608028654f;   // sqrt(2/pi)
    float t = tanhf(c * (x + 0.044715f * x * x * x));
    return 0.5f * x * (1.0f + t);
}

__device__ __forceinline__ float2 cmul(float2 a, float2 b) {
    return make_float2(a.x * b.x - a.y * b.y, a.x * b.y + a.y * b.x);
}

// ---------------------------------------------------------------------------
// fp32 -> bf16 cast (weights), 4 elements/thread
// ---------------------------------------------------------------------------
__global__ __launch_bounds__(256) void cast_bf16_kernel(
    const float* __restrict__ in, bf16_t* __restrict__ out)
{
    const int i = (blockIdx.x * 256 + threadIdx.x) * 4;
    const float4 v = *(const float4*)(in + i);
    bf16x4 o;
    o[0] = (bf16_t)v.x; o[1] = (bf16_t)v.y; o[2] = (bf16_t)v.z; o[3] = (bf16_t)v.w;
    *(bf16x4*)(out + i) = o;
}

// ---------------------------------------------------------------------------
// RMSNorm -> bf16 output: one block per row of 1024 floats
// ---------------------------------------------------------------------------
__global__ __launch_bounds__(256) void rmsnorm_bf16_kernel(
    const float* __restrict__ in, const float* __restrict__ w,
    bf16_t* __restrict__ out)
{
    const int row = blockIdx.x;
    const float4* ip = (const float4*)(in + (size_t)row * DD);
    float4 v = ip[threadIdx.x];
    float ss = v.x*v.x + v.y*v.y + v.z*v.z + v.w*v.w;
    #pragma unroll
    for (int off = 32; off > 0; off >>= 1) ss += __shfl_down(ss, off, 64);
    __shared__ float sums[4];
    const int wid = threadIdx.x >> 6;
    if ((threadIdx.x & 63) == 0) sums[wid] = ss;
    __syncthreads();
    const float tot = sums[0] + sums[1] + sums[2] + sums[3];
    const float scale = rsqrtf(tot * (1.0f / (float)DD) + 1e-8f);
    const float4 wv = ((const float4*)w)[threadIdx.x];
    bf16x4 o;
    o[0] = (bf16_t)(v.x * scale * wv.x);
    o[1] = (bf16_t)(v.y * scale * wv.y);
    o[2] = (bf16_t)(v.z * scale * wv.z);
    o[3] = (bf16_t)(v.w * scale * wv.w);
    *(bf16x4*)(out + (size_t)row * DD + threadIdx.x * 4) = o;
}

// ---------------------------------------------------------------------------
// bf16 MFMA GEMM: C(M,N) = epi(A(M,K) @ W(N,K)^T + bias) [+ res]
// 128x128 tile, BK=32, 256 thr (4 waves, 2x2), each wave 4x4 16x16x32 MFMA
// tiles, global_load_lds width=16 staging, ds_read_b128 fragments.
// EPI: 0 = bias, 1 = bias + residual, 2 = bias + tanh-GELU
// BIASROW: bias indexed by output row (for transposed-output GEMMs)
// ---------------------------------------------------------------------------
template<int EPI, bool BF16OUT, bool BIASROW = false>
__global__ __launch_bounds__(256) void gemm_mfma_kernel(
    const bf16_t* __restrict__ A,    // (M,K)
    const bf16_t* __restrict__ W,    // (N,K)
    const float* __restrict__ bias,  // (N) or (M) if BIASROW
    const float* __restrict__ res,   // (M,N) or nullptr
    float* __restrict__ Cf,          // fp32 out (if !BF16OUT)
    bf16_t* __restrict__ Cb,         // bf16 out (if BF16OUT)
    int M, int N, int K)
{
    __shared__ __align__(16) bf16_t As[128 * 32];
    __shared__ __align__(16) bf16_t Ws[128 * 32];
    const int tid  = threadIdx.x;
    const int bm   = blockIdx.y * 128;
    const int bn   = blockIdx.x * 128;
    const int lane = tid & 63;
    const int wave = tid >> 6;
    const int wr   = (wave >> 1) * 64;   // wave row offset within tile
    const int wc   = (wave & 1) * 64;    // wave col offset within tile

    const int lrow = tid >> 2;           // 0..63
    const int lcol = (tid & 3) * 8;      // 0,8,16,24 (bf16 elements)

    const bf16_t* Ag = A + (size_t)(bm + lrow) * K + lcol;
    const bf16_t* Wg = W + (size_t)(bn + lrow) * K + lcol;
    bf16_t* AsL0 = As + lrow * 32 + lcol;
    bf16_t* AsL1 = As + (64 + lrow) * 32 + lcol;
    bf16_t* WsL0 = Ws + lrow * 32 + lcol;
    bf16_t* WsL1 = Ws + (64 + lrow) * 32 + lcol;

    f32x4 acc[4][4] = {};

    const int fr = lane & 15;            // m (or n) within 16-tile
    const int fc = (lane >> 4) * 8;      // k offset (quad*8)

    for (int k0 = 0; k0 < K; k0 += 32) {
        GLD_LDS16(Ag + k0,                AsL0);
        GLD_LDS16(Ag + (size_t)64*K + k0, AsL1);
        GLD_LDS16(Wg + k0,                WsL0);
        GLD_LDS16(Wg + (size_t)64*K + k0, WsL1);
        __syncthreads();

        bf16x8 af[4], wf[4];
        #pragma unroll
        for (int i = 0; i < 4; ++i)
            af[i] = *(const bf16x8*)(As + (wr + i*16 + fr) * 32 + fc);
        #pragma unroll
        for (int j = 0; j < 4; ++j)
            wf[j] = *(const bf16x8*)(Ws + (wc + j*16 + fr) * 32 + fc);
        #pragma unroll
        for (int i = 0; i < 4; ++i)
            #pragma unroll
            for (int j = 0; j < 4; ++j)
                acc[i][j] = __builtin_amdgcn_mfma_f32_16x16x32_bf16(
                    af[i], wf[j], acc[i][j], 0, 0, 0);
        __syncthreads();
    }

    // Epilogue. C/D layout: col = lane&15, row = (lane>>4)*4 + reg
    const int fq = lane >> 4;
    #pragma unroll
    for (int i = 0; i < 4; ++i) {
        const int row0 = bm + wr + i*16 + fq*4;
        #pragma unroll
        for (int j = 0; j < 4; ++j) {
            const int col = bn + wc + j*16 + fr;
            const float bcol = BIASROW ? 0.0f : bias[col];
            #pragma unroll
            for (int r = 0; r < 4; ++r) {
                float v = acc[i][j][r] + (BIASROW ? bias[row0 + r] : bcol);
                if constexpr (EPI == 2) v = gelu_tanh(v);
                if constexpr (EPI == 1) v += res[(size_t)(row0 + r) * N + col];
                if constexpr (BF16OUT)
                    Cb[(size_t)(row0 + r) * N + col] = (bf16_t)v;
                else
                    Cf[(size_t)(row0 + r) * N + col] = v;
            }
        }
    }
}

// ---------------------------------------------------------------------------
// Depthwise causal k=3 short filter on u_t (3D, M) channel-major, producing
//   x0t (D, M)  (layout (D,B,L)) = conv channels [0,D)
//   vin (D, M)  (layout (D,B,L)) = conv[2D..3D) * conv[D..2D)
// One block per d; fully coalesced reads and writes, no LDS.
// ---------------------------------------------------------------------------
__global__ __launch_bounds__(256) void shortfilter_kernel(
    const float* __restrict__ ut, const float* __restrict__ sw,
    const float* __restrict__ sb, float* __restrict__ x0t,
    float* __restrict__ vin)
{
    const int d = blockIdx.x;             // 0..1023
    const int c0 = d, c1 = DD + d, c2 = 2 * DD + d;
    const float w0a = sw[c0*3+0], w0b = sw[c0*3+1], w0c = sw[c0*3+2], b0 = sb[c0];
    const float w1a = sw[c1*3+0], w1b = sw[c1*3+1], w1c = sw[c1*3+2], b1 = sb[c1];
    const float w2a = sw[c2*3+0], w2b = sw[c2*3+1], w2c = sw[c2*3+2], b2 = sb[c2];
    const float* r0 = ut + (size_t)c0 * MM;
    const float* r1 = ut + (size_t)c1 * MM;
    const float* r2 = ut + (size_t)c2 * MM;
    float* o0 = x0t + (size_t)d * MM;
    float* o1 = vin + (size_t)d * MM;
    for (int m = threadIdx.x; m < MM; m += 256) {
        const int l = m & (LL - 1);
        float v0 = w0c * r0[m] + b0;
        float v1 = w1c * r1[m] + b1;
        float v2 = w2c * r2[m] + b2;
        if (l >= 1) {
            v0 += w0b * r0[m-1]; v1 += w1b * r1[m-1]; v2 += w2b * r2[m-1];
        }
        if (l >= 2) {
            v0 += w0a * r0[m-2]; v1 += w1a * r1[m-2]; v2 += w2a * r2[m-2];
        }
        o0[m] = v0;
        o1[m] = v2 * v1;
    }
}

// ---------------------------------------------------------------------------
// Implicit filter MLP, phase 1: h2t (64, L). One thread per position l.
// w2 staged in LDS (broadcast reads); h1 in registers; coalesced h2t stores.
// ---------------------------------------------------------------------------
__global__ __launch_bounds__(256) void filtermlp_kernel(
    const float* __restrict__ w1, const float* __restrict__ b1,
    const float* __restrict__ f1, const float* __restrict__ w2,
    const float* __restrict__ b2, const float* __restrict__ f2,
    float* __restrict__ h2t)
{
    __shared__ float w2s[64 * 64];      // 16 KB
    for (int i = threadIdx.x; i < 64 * 64; i += 256) w2s[i] = w2[i];
    __syncthreads();
    const int l = blockIdx.x * 256 + threadIdx.x;   // 0..2047
    const float t = (float)l / (float)(LL - 1);
    const float ang = 1e-4f * 6.283185307179586f * (float)l / (float)LL;
    const float z0 = t, z1 = cosf(ang), z2 = -sinf(ang);
    float h1[64];
    #pragma unroll
    for (int j = 0; j < 64; ++j) {
        const float s = w1[j*3+0]*z0 + w1[j*3+1]*z1 + w1[j*3+2]*z2 + b1[j];
        h1[j] = sinf(f1[j] * s);
    }
    for (int j = 0; j < 64; ++j) {
        float s = b2[j];
        #pragma unroll 16
        for (int jj = 0; jj < 64; ++jj) s += w2s[j*64 + jj] * h1[jj];
        h2t[j * LL + l] = sinf(f2[j] * s);
    }
}

// ---------------------------------------------------------------------------
// Implicit filter, phase 2: kfilt[d][l] = (w3[d,:] . h2t[:,l]) * exp(-t|delta_d|)
// Tile: 32 d x 256 l per block. w3 tile in LDS (broadcast), h2t coalesced.
// ---------------------------------------------------------------------------
__global__ __launch_bounds__(256) void filtermod_kernel(
    const float* __restrict__ w3, const float* __restrict__ h2t,
    float* __restrict__ kfilt)
{
    __shared__ float w3s[32 * 64];      // 8 KB
    const int d0 = blockIdx.y * 32;
    const int l  = blockIdx.x * 256 + threadIdx.x;
    for (int i = threadIdx.x; i < 32 * 64; i += 256) w3s[i] = w3[d0 * 64 + i];
    __syncthreads();
    float acc[32] = {};
    for (int j = 0; j < 64; ++j) {
        const float v = h2t[j * LL + l];
        #pragma unroll
        for (int dd = 0; dd < 32; ++dd) acc[dd] += w3s[dd*64 + j] * v;
    }
    const float t = (float)l / (float)(LL - 1);
    const float min_decay = -3.0701134573253944f;   // ln(1e-2)/1.5
    const float max_decay = -15.350567286626972f;   // ln(1e-2)/0.3
    #pragma unroll
    for (int dd = 0; dd < 32; ++dd) {
        const int d = d0 + dd;
        const float delta = fabsf(min_decay + (max_decay - min_decay) * (float)d / (float)(DD - 1));
        kfilt[(size_t)d * LL + l] = acc[dd] * expf(-t * delta);
    }
}

// ---------------------------------------------------------------------------
// 4096-point complex Stockham radix-4 FFT in LDS (6 stages, autosort).
// SIGN = -1 forward, +1 unnormalized inverse. NT threads, 1024/NT
// butterflies each. All LDS indices pass through SWZ (bank uniformity).
// ---------------------------------------------------------------------------
template<int NT, int SIGN>
__device__ __forceinline__ int fft4096_r4(float2 (*bufs)[4096], int cur)
{
    constexpr int NB = 1024 / NT;
    const float fsign = (float)SIGN;
    #pragma unroll
    for (int t = 0; t < 6; ++t) {
        const int ls = 2 * t;                        // log2(stride)
        const float theta = fsign * 6.283185307179586f / (float)(4096 >> ls);
        float2* __restrict__ src = bufs[cur];
        float2* __restrict__ dst = bufs[cur ^ 1];
        #pragma unroll
        for (int it = 0; it < NB; ++it) {
            const int idx = (int)threadIdx.x + it * NT;   // 0..1023
            const int p = idx >> ls;
            const int q = idx & ((1 << ls) - 1);
            const float2 a0 = src[SWZ(idx)];
            const float2 a1 = src[SWZ(idx + 1024)];
            const float2 a2 = src[SWZ(idx + 2048)];
            const float2 a3 = src[SWZ(idx + 3072)];
            float sn, cs;
            __sincosf(theta * (float)p, &sn, &cs);
            const float2 W  = make_float2(cs, sn);
            const float2 W2 = make_float2(cs*cs - sn*sn, 2.0f*cs*sn);
            const float2 u0 = make_float2(a0.x + a2.x, a0.y + a2.y);
            const float2 u1 = make_float2(a1.x + a3.x, a1.y + a3.y);
            const float2 t2 = make_float2(a0.x - a2.x, a0.y - a2.y);
            const float2 t3 = make_float2(a1.x - a3.x, a1.y - a3.y);
            const float2 u2 = cmul(W, t2);
            const float2 it3 = make_float2(-fsign * t3.y, fsign * t3.x);
            const float2 u3 = cmul(W, it3);
            const int o = q + (p << (ls + 2));
            dst[SWZ(o)]             = make_float2(u0.x + u1.x, u0.y + u1.y);
            dst[SWZ(o + (1 << ls))] = make_float2(u2.x + u3.x, u2.y + u3.y);
            dst[SWZ(o + (2 << ls))] = cmul(make_float2(u0.x - u1.x, u0.y - u1.y), W2);
            dst[SWZ(o + (3 << ls))] = cmul(make_float2(u2.x - u3.x, u2.y - u3.y), W2);
        }
        __syncthreads();
        cur ^= 1;
    }
    return cur;
}

// ---------------------------------------------------------------------------
// FFT of filter rows, two real rows per block (z = k_{2d} + i*k_{2d+1}).
// Half-spectra extracted via conjugate symmetry; /4096 folded in.
// ---------------------------------------------------------------------------
__global__ __launch_bounds__(512) void kfft_kernel(
    const float* __restrict__ kfilt, float2* __restrict__ Kf)
{
    __shared__ float2 fb[2][4096];
    const int d0 = blockIdx.x * 2;
    const float* k0 = kfilt + (size_t)d0 * LL;
    const float* k1 = k0 + LL;
    const float inv = 1.0f / 4096.0f;
    const int tid = threadIdx.x;
    for (int i = tid; i < 2048; i += 512) {
        fb[0][SWZ(i)]        = make_float2(k0[i] * inv, k1[i] * inv);
        fb[0][SWZ(i + 2048)] = make_float2(0.f, 0.f);
    }
    __syncthreads();
    const int cur = fft4096_r4<512, -1>(fb, 0);
    float2* o0 = Kf + (size_t)d0 * KF_STRIDE;
    float2* o1 = o0 + KF_STRIDE;
    for (int k = tid; k <= 2048; k += 512) {
        const float2 z1 = fb[cur][SWZ(k)];
        const float2 z2 = fb[cur][SWZ((4096 - k) & 4095)];
        o0[k] = make_float2(0.5f * (z1.x + z2.x), 0.5f * (z1.y - z2.y));
        o1[k] = make_float2(0.5f * (z1.y + z2.y), 0.5f * (z2.x - z1.x));
    }
}

// ---------------------------------------------------------------------------
// Long conv, two real rows per block: z = v1 + i*v2, filter k is REAL.
// vio layout (D, B, L): row r = d*B + b. Block blk handles rows 2blk, 2blk+1
// (same d = blk>>1, adjacent b). In place + bias.
// ---------------------------------------------------------------------------
__global__ __launch_bounds__(512) void fftconv_kernel(
    float* __restrict__ vio, const float2* __restrict__ Kf,
    const float* __restrict__ fbias)
{
    __shared__ float2 fb[2][4096];
    const int blk = blockIdx.x;          // [0, 2048)
    const int d   = blk >> 1;
    float* v1 = vio + (size_t)(2 * blk) * LL;
    float* v2 = v1 + LL;
    const int tid = threadIdx.x;
    for (int i = tid; i < 2048; i += 512) {
        fb[0][SWZ(i)]        = make_float2(v1[i], v2[i]);
        fb[0][SWZ(i + 2048)] = make_float2(0.f, 0.f);
    }
    __syncthreads();
    int cur = fft4096_r4<512, -1>(fb, 0);
    const float2* kf = Kf + (size_t)d * KF_STRIDE;
    for (int i = tid; i < 4096; i += 512) {
        const float2 a = fb[cur][SWZ(i)];
        float2 k;
        if (i <= 2048) k = kf[i];
        else { const float2 t = kf[4096 - i]; k = make_float2(t.x, -t.y); }
        fb[cur][SWZ(i)] = cmul(a, k);
    }
    __syncthreads();
    cur = fft4096_r4<512, 1>(fb, cur);
    const float bias = fbias[d];
    for (int i = tid; i < 2048; i += 512) {
        const float2 zy = fb[cur][SWZ(i)];
        v1[i] = zy.x + bias * v1[i];
        v2[i] = zy.y + bias * v2[i];
    }
}

// ---------------------------------------------------------------------------
// gated_bf16(B,L,D) = bf16( y(D,B,L) * x0t(D,B,L) )  -- LDS 32x32 transpose
// ---------------------------------------------------------------------------
__global__ __launch_bounds__(256) void gate_transpose_kernel(
    const float* __restrict__ y, const float* __restrict__ x0t,
    bf16_t* __restrict__ g)
{
    __shared__ float tile[32][33];
    const int b  = blockIdx.z;
    const int l0 = blockIdx.x * 32;
    const int d0 = blockIdx.y * 32;
    const int tx  = threadIdx.x & 31;
    const int tyb = threadIdx.x >> 5;    // 0..7
    #pragma unroll
    for (int i = 0; i < 4; ++i) {
        const int dy = tyb + i * 8;
        const size_t src = ((size_t)(d0 + dy) * BB + b) * LL + l0 + tx;
        tile[dy][tx] = y[src] * x0t[src];
    }
    __syncthreads();
    #pragma unroll
    for (int i = 0; i < 4; ++i) {
        const int ly = tyb + i * 8;
        g[((size_t)(b * LL + l0 + ly)) * DD + d0 + tx] = (bf16_t)tile[tx][ly];
    }
}

// ---------------------------------------------------------------------------
// Launch
// ---------------------------------------------------------------------------
extern "C" void kernel_launch(void* const* d_in, const int* in_sizes, int n_in,
                              void* d_out, int out_size, void* d_ws, size_t ws_size,
                              hipStream_t stream)
{
    (void)in_sizes; (void)n_in; (void)out_size; (void)ws_size;
    const float* x   = (const float*)d_in[0];
    const float* nw0 = (const float*)d_in[1];
    const float* ipw = (const float*)d_in[2];
    const float* ipb = (const float*)d_in[3];
    const float* sfw = (const float*)d_in[4];
    const float* sfb = (const float*)d_in[5];
    const float* w1  = (const float*)d_in[6];
    const float* b1  = (const float*)d_in[7];
    const float* f1  = (const float*)d_in[8];
    const float* w2  = (const float*)d_in[9];
    const float* b2  = (const float*)d_in[10];
    const float* f2  = (const float*)d_in[11];
    const float* w3  = (const float*)d_in[12];
    const float* fbv = (const float*)d_in[13];
    const float* opw = (const float*)d_in[14];
    const float* opb = (const float*)d_in[15];
    const float* nw1 = (const float*)d_in[16];
    const float* fw1 = (const float*)d_in[17];
    const float* fb1 = (const float*)d_in[18];
    const float* fw2 = (const float*)d_in[19];
    const float* fb2 = (const float*)d_in[20];
    float* out = (float*)d_out;

    float* ws = (float*)d_ws;
    // Region 0: u_t (3D, M) fp32 = 25,165,824 f. After shortfilter consumes
    // u_t, the region holds: gated_bf16 (8M bf16), h (8M f), mid_bf16 (16M bf16)
    float*  ut     = ws;
    bf16_t* gatedb = (bf16_t*)ws;                       // 8,388,608 bf16
    float*  h      = ws + 4194304;                      // 8,388,608 f
    bf16_t* midb   = (bf16_t*)(ws + 12582912);          // 16,777,216 bf16
    bf16_t* xnb    = (bf16_t*)(ws + 25165824);          // 8M bf16 (also hn later)
    float*  x0t    = ws + 29360128;                     // 8,388,608 f (D,B,L)
    float*  vio    = ws + 37748736;                     // 8,388,608 f (D,B,L)
    float*  kfilt  = ws + 46137344;                     // 2,097,152 f
    float2* Kf     = (float2*)(ws + 48234496);          // 1024 x KF_STRIDE cplx
    bf16_t* ipwb   = (bf16_t*)(ws + 52445184);          // 3,145,728 bf16
    bf16_t* opwb   = ipwb + 3145728;                    // 1,048,576 bf16
    bf16_t* fw1b   = opwb + 1048576;                    // 2,097,152 bf16
    bf16_t* fw2b   = fw1b + 2097152;                    // 2,097,152 bf16
    float*  h2t    = ws + 56639488;                     // (64, L) = 131,072 f
    // total: 56,770,560 f = 227.1 MB

    // 0. weight casts
    cast_bf16_kernel<<<3072*1024/1024, 256, 0, stream>>>(ipw, ipwb);
    cast_bf16_kernel<<<1024*1024/1024, 256, 0, stream>>>(opw, opwb);
    cast_bf16_kernel<<<2048*1024/1024, 256, 0, stream>>>(fw1, fw1b);
    cast_bf16_kernel<<<2048*1024/1024, 256, 0, stream>>>(fw2, fw2b);
    // 1. implicit filter: MLP phase (h2t), modulation phase (kfilt), FFT (Kf)
    filtermlp_kernel<<<LL/256, 256, 0, stream>>>(w1, b1, f1, w2, b2, f2, h2t);
    filtermod_kernel<<<dim3(LL/256, DD/32), 256, 0, stream>>>(w3, h2t, kfilt);
    kfft_kernel<<<DD/2, 512, 0, stream>>>(kfilt, Kf);
    // 2. xn = bf16(rmsnorm(x, norm_in_w))
    rmsnorm_bf16_kernel<<<MM, 256, 0, stream>>>(x, nw0, xnb);
    // 3. u_t = in_proj_w @ xn^T + b (transposed output: rows = channels)
    gemm_mfma_kernel<0, false, true><<<dim3(MM/128, 3072/128), 256, 0, stream>>>(
        ipwb, xnb, ipb, nullptr, ut, nullptr, 3*DD, MM, DD);
    // 4. short filter -> x0t (D,B,L), vin (D,B,L); coalesced both ways
    shortfilter_kernel<<<DD, 256, 0, stream>>>(ut, sfw, sfb, x0t, vio);
    // 5. vio <- causal_conv(vio, k) + filter_bias * vio   (2 rows per block)
    fftconv_kernel<<<BB*DD/2, 512, 0, stream>>>(vio, Kf, fbv);
    // 6. gated_bf16(B,L,D) = y * x0
    gate_transpose_kernel<<<dim3(LL/32, DD/32, BB), 256, 0, stream>>>(vio, x0t, gatedb);
    // 7. h = gated @ out_proj_w^T + b + x   (M=8192, N=1024, K=1024)
    gemm_mfma_kernel<1, false><<<dim3(DD/128, MM/128), 256, 0, stream>>>(
        gatedb, opwb, opb, x, h, nullptr, MM, DD, DD);
    // 8. hn = bf16(rmsnorm(h, norm_w))
    rmsnorm_bf16_kernel<<<MM, 256, 0, stream>>>(h, nw1, xnb);
    // 9. mid = bf16(gelu(hn @ ffn_w1^T + b))  (M=8192, N=2048, K=1024)
    gemm_mfma_kernel<2, true><<<dim3(2*DD/128, MM/128), 256, 0, stream>>>(
        xnb, fw1b, fb1, nullptr, nullptr, midb, MM, 2*DD, DD);
    // 10. out = mid @ ffn_w2^T + b + h      (M=8192, N=1024, K=2048)
    gemm_mfma_kernel<1, false><<<dim3(DD/128, MM/128), 256, 0, stream>>>(
        midb, fw2b, fb2, h, out, nullptr, MM, DD, 2*DD);
}

// Round 6
// 613.300 us; speedup vs baseline: 1.1267x; 1.1267x over previous
//
#include <hip/hip_runtime.h>
#include <hip/hip_bf16.h>
#include <cstddef>

// ---------------------------------------------------------------------------
// Constants for this problem: B=4, L=2048, D=1024
// ---------------------------------------------------------------------------
#define BB 4
#define LL 2048
#define DD 1024
#define MM (BB*LL)          // 8192 tokens
#define KF_STRIDE 2056      // complex elements per Kf row (>= 2049, 16B-aligned)

// LDS bank swizzle for float2 arrays: makes all Stockham read/write streams
// uniform across the 16 bank-pairs. Modifies bits 2-3 only (stays in range).
#define SWZ(a) ((a) ^ (((a) >> 4) & 12))

typedef __bf16 bf16_t;
typedef __attribute__((ext_vector_type(8))) __bf16 bf16x8;
typedef __attribute__((ext_vector_type(4))) __bf16 bf16x4;
typedef __attribute__((ext_vector_type(4))) float f32x4;

// async global->LDS, 16 bytes per lane (global_load_lds_dwordx4)
#define GLD_LDS16(gp, lp) __builtin_amdgcn_global_load_lds(                 \
    (const __attribute__((address_space(1))) unsigned int*)(gp),            \
    (__attribute__((address_space(3))) unsigned int*)(lp), 16, 0, 0)

__device__ __forceinline__ float gelu_tanh(float x) {
    const float c = 0.7978845608028654f;   // sqrt(2/pi)
    float t = tanhf(c * (x + 0.044715f * x * x * x));
    return 0.5f * x * (1.0f + t);
}

__device__ __forceinline__ float2 cmul(float2 a, float2 b) {
    return make_float2(a.x * b.x - a.y * b.y, a.x * b.y + a.y * b.x);
}

// ---------------------------------------------------------------------------
// fp32 -> bf16 cast (weights), 4 elements/thread
// ---------------------------------------------------------------------------
__global__ __launch_bounds__(256) void cast_bf16_kernel(
    const float* __restrict__ in, bf16_t* __restrict__ out)
{
    const int i = (blockIdx.x * 256 + threadIdx.x) * 4;
    const float4 v = *(const float4*)(in + i);
    bf16x4 o;
    o[0] = (bf16_t)v.x; o[1] = (bf16_t)v.y; o[2] = (bf16_t)v.z; o[3] = (bf16_t)v.w;
    *(bf16x4*)(out + i) = o;
}

// ---------------------------------------------------------------------------
// RMSNorm -> bf16 output: one block per row of 1024 floats
// ---------------------------------------------------------------------------
__global__ __launch_bounds__(256) void rmsnorm_bf16_kernel(
    const float* __restrict__ in, const float* __restrict__ w,
    bf16_t* __restrict__ out)
{
    const int row = blockIdx.x;
    const float4* ip = (const float4*)(in + (size_t)row * DD);
    float4 v = ip[threadIdx.x];
    float ss = v.x*v.x + v.y*v.y + v.z*v.z + v.w*v.w;
    #pragma unroll
    for (int off = 32; off > 0; off >>= 1) ss += __shfl_down(ss, off, 64);
    __shared__ float sums[4];
    const int wid = threadIdx.x >> 6;
    if ((threadIdx.x & 63) == 0) sums[wid] = ss;
    __syncthreads();
    const float tot = sums[0] + sums[1] + sums[2] + sums[3];
    const float scale = rsqrtf(tot * (1.0f / (float)DD) + 1e-8f);
    const float4 wv = ((const float4*)w)[threadIdx.x];
    bf16x4 o;
    o[0] = (bf16_t)(v.x * scale * wv.x);
    o[1] = (bf16_t)(v.y * scale * wv.y);
    o[2] = (bf16_t)(v.z * scale * wv.z);
    o[3] = (bf16_t)(v.w * scale * wv.w);
    *(bf16x4*)(out + (size_t)row * DD + threadIdx.x * 4) = o;
}

// ---------------------------------------------------------------------------
// bf16 MFMA GEMM: C(M,N) = epi(A(M,K) @ W(N,K)^T + bias) [+ res]
// 128x128 tile, BK=32, 256 thr (4 waves, 2x2), each wave 4x4 16x16x32 MFMA
// tiles, global_load_lds width=16 staging, ds_read_b128 fragments.
// EPI: 0 = bias, 1 = bias + residual, 2 = bias + tanh-GELU
// BIASROW: bias indexed by output row (for transposed-output GEMMs)
// ---------------------------------------------------------------------------
template<int EPI, bool BF16OUT, bool BIASROW = false>
__global__ __launch_bounds__(256) void gemm_mfma_kernel(
    const bf16_t* __restrict__ A,    // (M,K)
    const bf16_t* __restrict__ W,    // (N,K)
    const float* __restrict__ bias,  // (N) or (M) if BIASROW
    const float* __restrict__ res,   // (M,N) or nullptr
    float* __restrict__ Cf,          // fp32 out (if !BF16OUT)
    bf16_t* __restrict__ Cb,         // bf16 out (if BF16OUT)
    int M, int N, int K)
{
    __shared__ __align__(16) bf16_t As[128 * 32];
    __shared__ __align__(16) bf16_t Ws[128 * 32];
    const int tid  = threadIdx.x;
    const int bm   = blockIdx.y * 128;
    const int bn   = blockIdx.x * 128;
    const int lane = tid & 63;
    const int wave = tid >> 6;
    const int wr   = (wave >> 1) * 64;   // wave row offset within tile
    const int wc   = (wave & 1) * 64;    // wave col offset within tile

    const int lrow = tid >> 2;           // 0..63
    const int lcol = (tid & 3) * 8;      // 0,8,16,24 (bf16 elements)

    const bf16_t* Ag = A + (size_t)(bm + lrow) * K + lcol;
    const bf16_t* Wg = W + (size_t)(bn + lrow) * K + lcol;
    bf16_t* AsL0 = As + lrow * 32 + lcol;
    bf16_t* AsL1 = As + (64 + lrow) * 32 + lcol;
    bf16_t* WsL0 = Ws + lrow * 32 + lcol;
    bf16_t* WsL1 = Ws + (64 + lrow) * 32 + lcol;

    f32x4 acc[4][4] = {};

    const int fr = lane & 15;            // m (or n) within 16-tile
    const int fc = (lane >> 4) * 8;      // k offset (quad*8)

    for (int k0 = 0; k0 < K; k0 += 32) {
        GLD_LDS16(Ag + k0,                AsL0);
        GLD_LDS16(Ag + (size_t)64*K + k0, AsL1);
        GLD_LDS16(Wg + k0,                WsL0);
        GLD_LDS16(Wg + (size_t)64*K + k0, WsL1);
        __syncthreads();

        bf16x8 af[4], wf[4];
        #pragma unroll
        for (int i = 0; i < 4; ++i)
            af[i] = *(const bf16x8*)(As + (wr + i*16 + fr) * 32 + fc);
        #pragma unroll
        for (int j = 0; j < 4; ++j)
            wf[j] = *(const bf16x8*)(Ws + (wc + j*16 + fr) * 32 + fc);
        #pragma unroll
        for (int i = 0; i < 4; ++i)
            #pragma unroll
            for (int j = 0; j < 4; ++j)
                acc[i][j] = __builtin_amdgcn_mfma_f32_16x16x32_bf16(
                    af[i], wf[j], acc[i][j], 0, 0, 0);
        __syncthreads();
    }

    // Epilogue. C/D layout: col = lane&15, row = (lane>>4)*4 + reg
    const int fq = lane >> 4;
    #pragma unroll
    for (int i = 0; i < 4; ++i) {
        const int row0 = bm + wr + i*16 + fq*4;
        #pragma unroll
        for (int j = 0; j < 4; ++j) {
            const int col = bn + wc + j*16 + fr;
            const float bcol = BIASROW ? 0.0f : bias[col];
            #pragma unroll
            for (int r = 0; r < 4; ++r) {
                float v = acc[i][j][r] + (BIASROW ? bias[row0 + r] : bcol);
                if constexpr (EPI == 2) v = gelu_tanh(v);
                if constexpr (EPI == 1) v += res[(size_t)(row0 + r) * N + col];
                if constexpr (BF16OUT)
                    Cb[(size_t)(row0 + r) * N + col] = (bf16_t)v;
                else
                    Cf[(size_t)(row0 + r) * N + col] = v;
            }
        }
    }
}

// ---------------------------------------------------------------------------
// Depthwise causal k=3 short filter on u_t (3D, M) channel-major, producing
//   x0t (D, M)  (layout (D,B,L)) = conv channels [0,D)
//   vin (D, M)  (layout (D,B,L)) = conv[2D..3D) * conv[D..2D)
// One block per d; fully coalesced reads and writes, no LDS.
// ---------------------------------------------------------------------------
__global__ __launch_bounds__(256) void shortfilter_kernel(
    const float* __restrict__ ut, const float* __restrict__ sw,
    const float* __restrict__ sb, float* __restrict__ x0t,
    float* __restrict__ vin)
{
    const int d = blockIdx.x;             // 0..1023
    const int c0 = d, c1 = DD + d, c2 = 2 * DD + d;
    const float w0a = sw[c0*3+0], w0b = sw[c0*3+1], w0c = sw[c0*3+2], b0 = sb[c0];
    const float w1a = sw[c1*3+0], w1b = sw[c1*3+1], w1c = sw[c1*3+2], b1 = sb[c1];
    const float w2a = sw[c2*3+0], w2b = sw[c2*3+1], w2c = sw[c2*3+2], b2 = sb[c2];
    const float* r0 = ut + (size_t)c0 * MM;
    const float* r1 = ut + (size_t)c1 * MM;
    const float* r2 = ut + (size_t)c2 * MM;
    float* o0 = x0t + (size_t)d * MM;
    float* o1 = vin + (size_t)d * MM;
    for (int m = threadIdx.x; m < MM; m += 256) {
        const int l = m & (LL - 1);
        float v0 = w0c * r0[m] + b0;
        float v1 = w1c * r1[m] + b1;
        float v2 = w2c * r2[m] + b2;
        if (l >= 1) {
            v0 += w0b * r0[m-1]; v1 += w1b * r1[m-1]; v2 += w2b * r2[m-1];
        }
        if (l >= 2) {
            v0 += w0a * r0[m-2]; v1 += w1a * r1[m-2]; v2 += w2a * r2[m-2];
        }
        o0[m] = v0;
        o1[m] = v2 * v1;
    }
}

// ---------------------------------------------------------------------------
// Implicit filter MLP, phase 1: h2t (64, L). One thread per position l.
// w2 staged in LDS (broadcast reads); h1 in registers (FULLY static indexing
// -- partial unroll spills to scratch, R5 lesson); coalesced h2t stores.
// ---------------------------------------------------------------------------
__global__ __launch_bounds__(256) void filtermlp_kernel(
    const float* __restrict__ w1, const float* __restrict__ b1,
    const float* __restrict__ f1, const float* __restrict__ w2,
    const float* __restrict__ b2, const float* __restrict__ f2,
    float* __restrict__ h2t)
{
    __shared__ float w2s[64 * 64];      // 16 KB
    for (int i = threadIdx.x; i < 64 * 64; i += 256) w2s[i] = w2[i];
    __syncthreads();
    const int l = blockIdx.x * 256 + threadIdx.x;   // 0..2047
    const float t = (float)l / (float)(LL - 1);
    const float ang = 1e-4f * 6.283185307179586f * (float)l / (float)LL;
    const float z0 = t, z1 = cosf(ang), z2 = -sinf(ang);
    float h1[64];
    #pragma unroll
    for (int j = 0; j < 64; ++j) {
        const float s = w1[j*3+0]*z0 + w1[j*3+1]*z1 + w1[j*3+2]*z2 + b1[j];
        h1[j] = sinf(f1[j] * s);
    }
    for (int j = 0; j < 64; ++j) {
        float s = b2[j];
        #pragma unroll   // FULL unroll: h1[jj] must be compile-time indexed
        for (int jj = 0; jj < 64; ++jj) s += w2s[j*64 + jj] * h1[jj];
        h2t[j * LL + l] = sinf(f2[j] * s);
    }
}

// ---------------------------------------------------------------------------
// Implicit filter, phase 2: kfilt[d][l] = (w3[d,:] . h2t[:,l]) * exp(-t|delta_d|)
// Tile: 32 d x 256 l per block. w3 tile in LDS (broadcast), h2t coalesced.
// ---------------------------------------------------------------------------
__global__ __launch_bounds__(256) void filtermod_kernel(
    const float* __restrict__ w3, const float* __restrict__ h2t,
    float* __restrict__ kfilt)
{
    __shared__ float w3s[32 * 64];      // 8 KB
    const int d0 = blockIdx.y * 32;
    const int l  = blockIdx.x * 256 + threadIdx.x;
    for (int i = threadIdx.x; i < 32 * 64; i += 256) w3s[i] = w3[d0 * 64 + i];
    __syncthreads();
    float acc[32] = {};
    for (int j = 0; j < 64; ++j) {
        const float v = h2t[j * LL + l];
        #pragma unroll
        for (int dd = 0; dd < 32; ++dd) acc[dd] += w3s[dd*64 + j] * v;
    }
    const float t = (float)l / (float)(LL - 1);
    const float min_decay = -3.0701134573253944f;   // ln(1e-2)/1.5
    const float max_decay = -15.350567286626972f;   // ln(1e-2)/0.3
    #pragma unroll
    for (int dd = 0; dd < 32; ++dd) {
        const int d = d0 + dd;
        const float delta = fabsf(min_decay + (max_decay - min_decay) * (float)d / (float)(DD - 1));
        kfilt[(size_t)d * LL + l] = acc[dd] * expf(-t * delta);
    }
}

// ---------------------------------------------------------------------------
// 4096-point complex Stockham radix-4 FFT in LDS (6 stages, autosort).
// SIGN = -1 forward, +1 unnormalized inverse. NT threads, 1024/NT
// butterflies each. All LDS indices pass through SWZ (bank uniformity).
// ---------------------------------------------------------------------------
template<int NT, int SIGN>
__device__ __forceinline__ int fft4096_r4(float2 (*bufs)[4096], int cur)
{
    constexpr int NB = 1024 / NT;
    const float fsign = (float)SIGN;
    #pragma unroll
    for (int t = 0; t < 6; ++t) {
        const int ls = 2 * t;                        // log2(stride)
        const float theta = fsign * 6.283185307179586f / (float)(4096 >> ls);
        float2* __restrict__ src = bufs[cur];
        float2* __restrict__ dst = bufs[cur ^ 1];
        #pragma unroll
        for (int it = 0; it < NB; ++it) {
            const int idx = (int)threadIdx.x + it * NT;   // 0..1023
            const int p = idx >> ls;
            const int q = idx & ((1 << ls) - 1);
            const float2 a0 = src[SWZ(idx)];
            const float2 a1 = src[SWZ(idx + 1024)];
            const float2 a2 = src[SWZ(idx + 2048)];
            const float2 a3 = src[SWZ(idx + 3072)];
            float sn, cs;
            __sincosf(theta * (float)p, &sn, &cs);
            const float2 W  = make_float2(cs, sn);
            const float2 W2 = make_float2(cs*cs - sn*sn, 2.0f*cs*sn);
            const float2 u0 = make_float2(a0.x + a2.x, a0.y + a2.y);
            const float2 u1 = make_float2(a1.x + a3.x, a1.y + a3.y);
            const float2 t2 = make_float2(a0.x - a2.x, a0.y - a2.y);
            const float2 t3 = make_float2(a1.x - a3.x, a1.y - a3.y);
            const float2 u2 = cmul(W, t2);
            const float2 it3 = make_float2(-fsign * t3.y, fsign * t3.x);
            const float2 u3 = cmul(W, it3);
            const int o = q + (p << (ls + 2));
            dst[SWZ(o)]             = make_float2(u0.x + u1.x, u0.y + u1.y);
            dst[SWZ(o + (1 << ls))] = make_float2(u2.x + u3.x, u2.y + u3.y);
            dst[SWZ(o + (2 << ls))] = cmul(make_float2(u0.x - u1.x, u0.y - u1.y), W2);
            dst[SWZ(o + (3 << ls))] = cmul(make_float2(u2.x - u3.x, u2.y - u3.y), W2);
        }
        __syncthreads();
        cur ^= 1;
    }
    return cur;
}

// ---------------------------------------------------------------------------
// FFT of filter rows, two real rows per block (z = k_{2d} + i*k_{2d+1}).
// Half-spectra extracted via conjugate symmetry; /4096 folded in.
// ---------------------------------------------------------------------------
__global__ __launch_bounds__(512) void kfft_kernel(
    const float* __restrict__ kfilt, float2* __restrict__ Kf)
{
    __shared__ float2 fb[2][4096];
    const int d0 = blockIdx.x * 2;
    const float* k0 = kfilt + (size_t)d0 * LL;
    const float* k1 = k0 + LL;
    const float inv = 1.0f / 4096.0f;
    const int tid = threadIdx.x;
    for (int i = tid; i < 2048; i += 512) {
        fb[0][SWZ(i)]        = make_float2(k0[i] * inv, k1[i] * inv);
        fb[0][SWZ(i + 2048)] = make_float2(0.f, 0.f);
    }
    __syncthreads();
    const int cur = fft4096_r4<512, -1>(fb, 0);
    float2* o0 = Kf + (size_t)d0 * KF_STRIDE;
    float2* o1 = o0 + KF_STRIDE;
    for (int k = tid; k <= 2048; k += 512) {
        const float2 z1 = fb[cur][SWZ(k)];
        const float2 z2 = fb[cur][SWZ((4096 - k) & 4095)];
        o0[k] = make_float2(0.5f * (z1.x + z2.x), 0.5f * (z1.y - z2.y));
        o1[k] = make_float2(0.5f * (z1.y + z2.y), 0.5f * (z2.x - z1.x));
    }
}

// ---------------------------------------------------------------------------
// Long conv, two real rows per block: z = v1 + i*v2, filter k is REAL.
// vio layout (D, B, L): row r = d*B + b. Block blk handles rows 2blk, 2blk+1
// (same d = blk>>1, adjacent b). In place + bias.
// ---------------------------------------------------------------------------
__global__ __launch_bounds__(512) void fftconv_kernel(
    float* __restrict__ vio, const float2* __restrict__ Kf,
    const float* __restrict__ fbias)
{
    __shared__ float2 fb[2][4096];
    const int blk = blockIdx.x;          // [0, 2048)
    const int d   = blk >> 1;
    float* v1 = vio + (size_t)(2 * blk) * LL;
    float* v2 = v1 + LL;
    const int tid = threadIdx.x;
    for (int i = tid; i < 2048; i += 512) {
        fb[0][SWZ(i)]        = make_float2(v1[i], v2[i]);
        fb[0][SWZ(i + 2048)] = make_float2(0.f, 0.f);
    }
    __syncthreads();
    int cur = fft4096_r4<512, -1>(fb, 0);
    const float2* kf = Kf + (size_t)d * KF_STRIDE;
    for (int i = tid; i < 4096; i += 512) {
        const float2 a = fb[cur][SWZ(i)];
        float2 k;
        if (i <= 2048) k = kf[i];
        else { const float2 t = kf[4096 - i]; k = make_float2(t.x, -t.y); }
        fb[cur][SWZ(i)] = cmul(a, k);
    }
    __syncthreads();
    cur = fft4096_r4<512, 1>(fb, cur);
    const float bias = fbias[d];
    for (int i = tid; i < 2048; i += 512) {
        const float2 zy = fb[cur][SWZ(i)];
        v1[i] = zy.x + bias * v1[i];
        v2[i] = zy.y + bias * v2[i];
    }
}

// ---------------------------------------------------------------------------
// gated_bf16(B,L,D) = bf16( y(D,B,L) * x0t(D,B,L) )  -- LDS 32x32 transpose
// ---------------------------------------------------------------------------
__global__ __launch_bounds__(256) void gate_transpose_kernel(
    const float* __restrict__ y, const float* __restrict__ x0t,
    bf16_t* __restrict__ g)
{
    __shared__ float tile[32][33];
    const int b  = blockIdx.z;
    const int l0 = blockIdx.x * 32;
    const int d0 = blockIdx.y * 32;
    const int tx  = threadIdx.x & 31;
    const int tyb = threadIdx.x >> 5;    // 0..7
    #pragma unroll
    for (int i = 0; i < 4; ++i) {
        const int dy = tyb + i * 8;
        const size_t src = ((size_t)(d0 + dy) * BB + b) * LL + l0 + tx;
        tile[dy][tx] = y[src] * x0t[src];
    }
    __syncthreads();
    #pragma unroll
    for (int i = 0; i < 4; ++i) {
        const int ly = tyb + i * 8;
        g[((size_t)(b * LL + l0 + ly)) * DD + d0 + tx] = (bf16_t)tile[tx][ly];
    }
}

// ---------------------------------------------------------------------------
// Launch
// ---------------------------------------------------------------------------
extern "C" void kernel_launch(void* const* d_in, const int* in_sizes, int n_in,
                              void* d_out, int out_size, void* d_ws, size_t ws_size,
                              hipStream_t stream)
{
    (void)in_sizes; (void)n_in; (void)out_size; (void)ws_size;
    const float* x   = (const float*)d_in[0];
    const float* nw0 = (const float*)d_in[1];
    const float* ipw = (const float*)d_in[2];
    const float* ipb = (const float*)d_in[3];
    const float* sfw = (const float*)d_in[4];
    const float* sfb = (const float*)d_in[5];
    const float* w1  = (const float*)d_in[6];
    const float* b1  = (const float*)d_in[7];
    const float* f1  = (const float*)d_in[8];
    const float* w2  = (const float*)d_in[9];
    const float* b2  = (const float*)d_in[10];
    const float* f2  = (const float*)d_in[11];
    const float* w3  = (const float*)d_in[12];
    const float* fbv = (const float*)d_in[13];
    const float* opw = (const float*)d_in[14];
    const float* opb = (const float*)d_in[15];
    const float* nw1 = (const float*)d_in[16];
    const float* fw1 = (const float*)d_in[17];
    const float* fb1 = (const float*)d_in[18];
    const float* fw2 = (const float*)d_in[19];
    const float* fb2 = (const float*)d_in[20];
    float* out = (float*)d_out;

    float* ws = (float*)d_ws;
    // Region 0: u_t (3D, M) fp32 = 25,165,824 f. After shortfilter consumes
    // u_t, the region holds: gated_bf16 (8M bf16), h (8M f), mid_bf16 (16M bf16)
    float*  ut     = ws;
    bf16_t* gatedb = (bf16_t*)ws;                       // 8,388,608 bf16
    float*  h      = ws + 4194304;                      // 8,388,608 f
    bf16_t* midb   = (bf16_t*)(ws + 12582912);          // 16,777,216 bf16
    bf16_t* xnb    = (bf16_t*)(ws + 25165824);          // 8M bf16 (also hn later)
    float*  x0t    = ws + 29360128;                     // 8,388,608 f (D,B,L)
    float*  vio    = ws + 37748736;                     // 8,388,608 f (D,B,L)
    float*  kfilt  = ws + 46137344;                     // 2,097,152 f
    float2* Kf     = (float2*)(ws + 48234496);          // 1024 x KF_STRIDE cplx
    bf16_t* ipwb   = (bf16_t*)(ws + 52445184);          // 3,145,728 bf16
    bf16_t* opwb   = ipwb + 3145728;                    // 1,048,576 bf16
    bf16_t* fw1b   = opwb + 1048576;                    // 2,097,152 bf16
    bf16_t* fw2b   = fw1b + 2097152;                    // 2,097,152 bf16
    float*  h2t    = ws + 56639488;                     // (64, L) = 131,072 f
    // total: 56,770,560 f = 227.1 MB

    // 0. weight casts
    cast_bf16_kernel<<<3072*1024/1024, 256, 0, stream>>>(ipw, ipwb);
    cast_bf16_kernel<<<1024*1024/1024, 256, 0, stream>>>(opw, opwb);
    cast_bf16_kernel<<<2048*1024/1024, 256, 0, stream>>>(fw1, fw1b);
    cast_bf16_kernel<<<2048*1024/1024, 256, 0, stream>>>(fw2, fw2b);
    // 1. implicit filter: MLP phase (h2t), modulation phase (kfilt), FFT (Kf)
    filtermlp_kernel<<<LL/256, 256, 0, stream>>>(w1, b1, f1, w2, b2, f2, h2t);
    filtermod_kernel<<<dim3(LL/256, DD/32), 256, 0, stream>>>(w3, h2t, kfilt);
    kfft_kernel<<<DD/2, 512, 0, stream>>>(kfilt, Kf);
    // 2. xn = bf16(rmsnorm(x, norm_in_w))
    rmsnorm_bf16_kernel<<<MM, 256, 0, stream>>>(x, nw0, xnb);
    // 3. u_t = in_proj_w @ xn^T + b (transposed output: rows = channels)
    gemm_mfma_kernel<0, false, true><<<dim3(MM/128, 3072/128), 256, 0, stream>>>(
        ipwb, xnb, ipb, nullptr, ut, nullptr, 3*DD, MM, DD);
    // 4. short filter -> x0t (D,B,L), vin (D,B,L); coalesced both ways
    shortfilter_kernel<<<DD, 256, 0, stream>>>(ut, sfw, sfb, x0t, vio);
    // 5. vio <- causal_conv(vio, k) + filter_bias * vio   (2 rows per block)
    fftconv_kernel<<<BB*DD/2, 512, 0, stream>>>(vio, Kf, fbv);
    // 6. gated_bf16(B,L,D) = y * x0
    gate_transpose_kernel<<<dim3(LL/32, DD/32, BB), 256, 0, stream>>>(vio, x0t, gatedb);
    // 7. h = gated @ out_proj_w^T + b + x   (M=8192, N=1024, K=1024)
    gemm_mfma_kernel<1, false><<<dim3(DD/128, MM/128), 256, 0, stream>>>(
        gatedb, opwb, opb, x, h, nullptr, MM, DD, DD);
    // 8. hn = bf16(rmsnorm(h, norm_w))
    rmsnorm_bf16_kernel<<<MM, 256, 0, stream>>>(h, nw1, xnb);
    // 9. mid = bf16(gelu(hn @ ffn_w1^T + b))  (M=8192, N=2048, K=1024)
    gemm_mfma_kernel<2, true><<<dim3(2*DD/128, MM/128), 256, 0, stream>>>(
        xnb, fw1b, fb1, nullptr, nullptr, midb, MM, 2*DD, DD);
    // 10. out = mid @ ffn_w2^T + b + h      (M=8192, N=1024, K=2048)
    gemm_mfma_kernel<1, false><<<dim3(DD/128, MM/128), 256, 0, stream>>>(
        midb, fw2b, fb2, h, out, nullptr, MM, DD, 2*DD);
}

// Round 7
// 589.637 us; speedup vs baseline: 1.1719x; 1.0401x over previous
//
#include <hip/hip_runtime.h>
#include <hip/hip_bf16.h>
#include <cstddef>

// ---------------------------------------------------------------------------
// Constants for this problem: B=4, L=2048, D=1024
// ---------------------------------------------------------------------------
#define BB 4
#define LL 2048
#define DD 1024
#define MM (BB*LL)          // 8192 tokens
#define KF_STRIDE 2056      // complex elements per Kf row (>= 2049, 16B-aligned)

// LDS bank swizzle for float2 arrays: makes all Stockham read/write streams
// uniform across the 16 bank-pairs. Modifies bits 2-3 only (stays in range).
#define SWZ(a) ((a) ^ (((a) >> 4) & 12))

typedef __bf16 bf16_t;
typedef __attribute__((ext_vector_type(8))) __bf16 bf16x8;
typedef __attribute__((ext_vector_type(4))) __bf16 bf16x4;
typedef __attribute__((ext_vector_type(4))) float f32x4;

// async global->LDS, 16 bytes per lane (global_load_lds_dwordx4)
#define GLD_LDS16(gp, lp) __builtin_amdgcn_global_load_lds(                 \
    (const __attribute__((address_space(1))) unsigned int*)(gp),            \
    (__attribute__((address_space(3))) unsigned int*)(lp), 16, 0, 0)

__device__ __forceinline__ float gelu_tanh(float x) {
    const float c = 0.7978845608028654f;   // sqrt(2/pi)
    float t = tanhf(c * (x + 0.044715f * x * x * x));
    return 0.5f * x * (1.0f + t);
}

__device__ __forceinline__ float2 cmul(float2 a, float2 b) {
    return make_float2(a.x * b.x - a.y * b.y, a.x * b.y + a.y * b.x);
}

// ---------------------------------------------------------------------------
// fp32 -> bf16 cast (weights), 4 elements/thread
// ---------------------------------------------------------------------------
__global__ __launch_bounds__(256) void cast_bf16_kernel(
    const float* __restrict__ in, bf16_t* __restrict__ out)
{
    const int i = (blockIdx.x * 256 + threadIdx.x) * 4;
    const float4 v = *(const float4*)(in + i);
    bf16x4 o;
    o[0] = (bf16_t)v.x; o[1] = (bf16_t)v.y; o[2] = (bf16_t)v.z; o[3] = (bf16_t)v.w;
    *(bf16x4*)(out + i) = o;
}

// ---------------------------------------------------------------------------
// RMSNorm -> bf16 output: one block per row of 1024 floats
// ---------------------------------------------------------------------------
__global__ __launch_bounds__(256) void rmsnorm_bf16_kernel(
    const float* __restrict__ in, const float* __restrict__ w,
    bf16_t* __restrict__ out)
{
    const int row = blockIdx.x;
    const float4* ip = (const float4*)(in + (size_t)row * DD);
    float4 v = ip[threadIdx.x];
    float ss = v.x*v.x + v.y*v.y + v.z*v.z + v.w*v.w;
    #pragma unroll
    for (int off = 32; off > 0; off >>= 1) ss += __shfl_down(ss, off, 64);
    __shared__ float sums[4];
    const int wid = threadIdx.x >> 6;
    if ((threadIdx.x & 63) == 0) sums[wid] = ss;
    __syncthreads();
    const float tot = sums[0] + sums[1] + sums[2] + sums[3];
    const float scale = rsqrtf(tot * (1.0f / (float)DD) + 1e-8f);
    const float4 wv = ((const float4*)w)[threadIdx.x];
    bf16x4 o;
    o[0] = (bf16_t)(v.x * scale * wv.x);
    o[1] = (bf16_t)(v.y * scale * wv.y);
    o[2] = (bf16_t)(v.z * scale * wv.z);
    o[3] = (bf16_t)(v.w * scale * wv.w);
    *(bf16x4*)(out + (size_t)row * DD + threadIdx.x * 4) = o;
}

// ---------------------------------------------------------------------------
// bf16 MFMA GEMM: C(M,N) = epi(A(M,K) @ W(N,K)^T + bias) [+ res]
// 128x128 tile, BK=32, 256 thr (4 waves, 2x2), each wave 4x4 16x16x32 MFMA
// tiles, global_load_lds width=16 staging, ds_read_b128 fragments.
// EPI: 0 = bias, 1 = bias + residual, 2 = bias + tanh-GELU
// BIASROW: bias indexed by output row (for transposed-output GEMMs)
// ---------------------------------------------------------------------------
template<int EPI, bool BF16OUT, bool BIASROW = false>
__global__ __launch_bounds__(256) void gemm_mfma_kernel(
    const bf16_t* __restrict__ A,    // (M,K)
    const bf16_t* __restrict__ W,    // (N,K)
    const float* __restrict__ bias,  // (N) or (M) if BIASROW
    const float* __restrict__ res,   // (M,N) or nullptr
    float* __restrict__ Cf,          // fp32 out (if !BF16OUT)
    bf16_t* __restrict__ Cb,         // bf16 out (if BF16OUT)
    int M, int N, int K)
{
    __shared__ __align__(16) bf16_t As[128 * 32];
    __shared__ __align__(16) bf16_t Ws[128 * 32];
    const int tid  = threadIdx.x;
    const int bm   = blockIdx.y * 128;
    const int bn   = blockIdx.x * 128;
    const int lane = tid & 63;
    const int wave = tid >> 6;
    const int wr   = (wave >> 1) * 64;   // wave row offset within tile
    const int wc   = (wave & 1) * 64;    // wave col offset within tile

    const int lrow = tid >> 2;           // 0..63
    const int lcol = (tid & 3) * 8;      // 0,8,16,24 (bf16 elements)

    const bf16_t* Ag = A + (size_t)(bm + lrow) * K + lcol;
    const bf16_t* Wg = W + (size_t)(bn + lrow) * K + lcol;
    bf16_t* AsL0 = As + lrow * 32 + lcol;
    bf16_t* AsL1 = As + (64 + lrow) * 32 + lcol;
    bf16_t* WsL0 = Ws + lrow * 32 + lcol;
    bf16_t* WsL1 = Ws + (64 + lrow) * 32 + lcol;

    f32x4 acc[4][4] = {};

    const int fr = lane & 15;            // m (or n) within 16-tile
    const int fc = (lane >> 4) * 8;      // k offset (quad*8)

    for (int k0 = 0; k0 < K; k0 += 32) {
        GLD_LDS16(Ag + k0,                AsL0);
        GLD_LDS16(Ag + (size_t)64*K + k0, AsL1);
        GLD_LDS16(Wg + k0,                WsL0);
        GLD_LDS16(Wg + (size_t)64*K + k0, WsL1);
        __syncthreads();

        bf16x8 af[4], wf[4];
        #pragma unroll
        for (int i = 0; i < 4; ++i)
            af[i] = *(const bf16x8*)(As + (wr + i*16 + fr) * 32 + fc);
        #pragma unroll
        for (int j = 0; j < 4; ++j)
            wf[j] = *(const bf16x8*)(Ws + (wc + j*16 + fr) * 32 + fc);
        #pragma unroll
        for (int i = 0; i < 4; ++i)
            #pragma unroll
            for (int j = 0; j < 4; ++j)
                acc[i][j] = __builtin_amdgcn_mfma_f32_16x16x32_bf16(
                    af[i], wf[j], acc[i][j], 0, 0, 0);
        __syncthreads();
    }

    // Epilogue. C/D layout: col = lane&15, row = (lane>>4)*4 + reg
    const int fq = lane >> 4;
    #pragma unroll
    for (int i = 0; i < 4; ++i) {
        const int row0 = bm + wr + i*16 + fq*4;
        #pragma unroll
        for (int j = 0; j < 4; ++j) {
            const int col = bn + wc + j*16 + fr;
            const float bcol = BIASROW ? 0.0f : bias[col];
            #pragma unroll
            for (int r = 0; r < 4; ++r) {
                float v = acc[i][j][r] + (BIASROW ? bias[row0 + r] : bcol);
                if constexpr (EPI == 2) v = gelu_tanh(v);
                if constexpr (EPI == 1) v += res[(size_t)(row0 + r) * N + col];
                if constexpr (BF16OUT)
                    Cb[(size_t)(row0 + r) * N + col] = (bf16_t)v;
                else
                    Cf[(size_t)(row0 + r) * N + col] = v;
            }
        }
    }
}

// ---------------------------------------------------------------------------
// Depthwise causal k=3 short filter on u_t (3D, M) channel-major bf16:
//   x0t (D, M) bf16  (layout (D,B,L)) = conv channels [0,D)
//   vin (D, M) fp32  (layout (D,B,L)) = conv[2D..3D) * conv[D..2D)
// One block per d; fully coalesced reads and writes, no LDS.
// ---------------------------------------------------------------------------
__global__ __launch_bounds__(256) void shortfilter_kernel(
    const bf16_t* __restrict__ ut, const float* __restrict__ sw,
    const float* __restrict__ sb, bf16_t* __restrict__ x0t,
    float* __restrict__ vin)
{
    const int d = blockIdx.x;             // 0..1023
    const int c0 = d, c1 = DD + d, c2 = 2 * DD + d;
    const float w0a = sw[c0*3+0], w0b = sw[c0*3+1], w0c = sw[c0*3+2], b0 = sb[c0];
    const float w1a = sw[c1*3+0], w1b = sw[c1*3+1], w1c = sw[c1*3+2], b1 = sb[c1];
    const float w2a = sw[c2*3+0], w2b = sw[c2*3+1], w2c = sw[c2*3+2], b2 = sb[c2];
    const bf16_t* r0 = ut + (size_t)c0 * MM;
    const bf16_t* r1 = ut + (size_t)c1 * MM;
    const bf16_t* r2 = ut + (size_t)c2 * MM;
    bf16_t* o0 = x0t + (size_t)d * MM;
    float*  o1 = vin + (size_t)d * MM;
    for (int m = threadIdx.x; m < MM; m += 256) {
        const int l = m & (LL - 1);
        float v0 = w0c * (float)r0[m] + b0;
        float v1 = w1c * (float)r1[m] + b1;
        float v2 = w2c * (float)r2[m] + b2;
        if (l >= 1) {
            v0 += w0b * (float)r0[m-1];
            v1 += w1b * (float)r1[m-1];
            v2 += w2b * (float)r2[m-1];
        }
        if (l >= 2) {
            v0 += w0a * (float)r0[m-2];
            v1 += w1a * (float)r1[m-2];
            v2 += w2a * (float)r2[m-2];
        }
        o0[m] = (bf16_t)v0;
        o1[m] = v2 * v1;
    }
}

// ---------------------------------------------------------------------------
// Implicit filter MLP, phase 1: h2t (64, L). One thread per position l.
// w2 staged in LDS (broadcast reads); h1 in registers (FULLY static indexing
// -- partial unroll spills to scratch, R5 lesson); coalesced h2t stores.
// ---------------------------------------------------------------------------
__global__ __launch_bounds__(256) void filtermlp_kernel(
    const float* __restrict__ w1, const float* __restrict__ b1,
    const float* __restrict__ f1, const float* __restrict__ w2,
    const float* __restrict__ b2, const float* __restrict__ f2,
    float* __restrict__ h2t)
{
    __shared__ float w2s[64 * 64];      // 16 KB
    for (int i = threadIdx.x; i < 64 * 64; i += 256) w2s[i] = w2[i];
    __syncthreads();
    const int l = blockIdx.x * 256 + threadIdx.x;   // 0..2047
    const float t = (float)l / (float)(LL - 1);
    const float ang = 1e-4f * 6.283185307179586f * (float)l / (float)LL;
    const float z0 = t, z1 = cosf(ang), z2 = -sinf(ang);
    float h1[64];
    #pragma unroll
    for (int j = 0; j < 64; ++j) {
        const float s = w1[j*3+0]*z0 + w1[j*3+1]*z1 + w1[j*3+2]*z2 + b1[j];
        h1[j] = sinf(f1[j] * s);
    }
    for (int j = 0; j < 64; ++j) {
        float s = b2[j];
        #pragma unroll   // FULL unroll: h1[jj] must be compile-time indexed
        for (int jj = 0; jj < 64; ++jj) s += w2s[j*64 + jj] * h1[jj];
        h2t[j * LL + l] = sinf(f2[j] * s);
    }
}

// ---------------------------------------------------------------------------
// Implicit filter, phase 2: kfilt[d][l] = (w3[d,:] . h2t[:,l]) * exp(-t|delta_d|)
// Tile: 32 d x 256 l per block. w3 tile in LDS (broadcast), h2t coalesced.
// ---------------------------------------------------------------------------
__global__ __launch_bounds__(256) void filtermod_kernel(
    const float* __restrict__ w3, const float* __restrict__ h2t,
    float* __restrict__ kfilt)
{
    __shared__ float w3s[32 * 64];      // 8 KB
    const int d0 = blockIdx.y * 32;
    const int l  = blockIdx.x * 256 + threadIdx.x;
    for (int i = threadIdx.x; i < 32 * 64; i += 256) w3s[i] = w3[d0 * 64 + i];
    __syncthreads();
    float acc[32] = {};
    for (int j = 0; j < 64; ++j) {
        const float v = h2t[j * LL + l];
        #pragma unroll
        for (int dd = 0; dd < 32; ++dd) acc[dd] += w3s[dd*64 + j] * v;
    }
    const float t = (float)l / (float)(LL - 1);
    const float min_decay = -3.0701134573253944f;   // ln(1e-2)/1.5
    const float max_decay = -15.350567286626972f;   // ln(1e-2)/0.3
    #pragma unroll
    for (int dd = 0; dd < 32; ++dd) {
        const int d = d0 + dd;
        const float delta = fabsf(min_decay + (max_decay - min_decay) * (float)d / (float)(DD - 1));
        kfilt[(size_t)d * LL + l] = acc[dd] * expf(-t * delta);
    }
}

// ---------------------------------------------------------------------------
// 4096-point complex Stockham radix-4 FFT, IN-PLACE in a single 32 KB LDS
// buffer (read-all / barrier / write-all per stage: each element is read and
// written by exactly one thread per stage, so this is race-free).
// Exactly 512 threads. SIGN = -1 forward, +1 unnormalized inverse.
// Ends with __syncthreads().
// ---------------------------------------------------------------------------
template<int SIGN>
__device__ __forceinline__ void fft4096_r4_ip(float2* __restrict__ buf)
{
    const float fsign = (float)SIGN;
    const int tid = threadIdx.x;          // 0..511
    #pragma unroll
    for (int t = 0; t < 6; ++t) {
        const int ls = 2 * t;                        // log2(stride)
        const float theta = fsign * 6.283185307179586f / (float)(4096 >> ls);
        float2 a[2][4];
        #pragma unroll
        for (int u = 0; u < 2; ++u) {
            const int idx = tid + u * 512;
            #pragma unroll
            for (int m = 0; m < 4; ++m)
                a[u][m] = buf[SWZ(idx + m * 1024)];
        }
        __syncthreads();
        #pragma unroll
        for (int u = 0; u < 2; ++u) {
            const int idx = tid + u * 512;
            const int p = idx >> ls;
            const int q = idx & ((1 << ls) - 1);
            float sn, cs;
            __sincosf(theta * (float)p, &sn, &cs);
            const float2 W  = make_float2(cs, sn);
            const float2 W2 = make_float2(cs*cs - sn*sn, 2.0f*cs*sn);
            const float2 u0 = make_float2(a[u][0].x + a[u][2].x, a[u][0].y + a[u][2].y);
            const float2 u1 = make_float2(a[u][1].x + a[u][3].x, a[u][1].y + a[u][3].y);
            const float2 t2 = make_float2(a[u][0].x - a[u][2].x, a[u][0].y - a[u][2].y);
            const float2 t3 = make_float2(a[u][1].x - a[u][3].x, a[u][1].y - a[u][3].y);
            const float2 u2 = cmul(W, t2);
            const float2 it3 = make_float2(-fsign * t3.y, fsign * t3.x);
            const float2 u3 = cmul(W, it3);
            const int o = q + (p << (ls + 2));
            buf[SWZ(o)]             = make_float2(u0.x + u1.x, u0.y + u1.y);
            buf[SWZ(o + (1 << ls))] = make_float2(u2.x + u3.x, u2.y + u3.y);
            buf[SWZ(o + (2 << ls))] = cmul(make_float2(u0.x - u1.x, u0.y - u1.y), W2);
            buf[SWZ(o + (3 << ls))] = cmul(make_float2(u2.x - u3.x, u2.y - u3.y), W2);
        }
        __syncthreads();
    }
}

// ---------------------------------------------------------------------------
// FFT of filter rows, two real rows per block (z = k_{2d} + i*k_{2d+1}).
// Half-spectra extracted via conjugate symmetry; /4096 folded in.
// ---------------------------------------------------------------------------
__global__ __launch_bounds__(512) void kfft_kernel(
    const float* __restrict__ kfilt, float2* __restrict__ Kf)
{
    __shared__ float2 fb[4096];           // 32 KB
    const int d0 = blockIdx.x * 2;
    const float* k0 = kfilt + (size_t)d0 * LL;
    const float* k1 = k0 + LL;
    const float inv = 1.0f / 4096.0f;
    const int tid = threadIdx.x;
    for (int i = tid; i < 2048; i += 512) {
        fb[SWZ(i)]        = make_float2(k0[i] * inv, k1[i] * inv);
        fb[SWZ(i + 2048)] = make_float2(0.f, 0.f);
    }
    __syncthreads();
    fft4096_r4_ip<-1>(fb);
    float2* o0 = Kf + (size_t)d0 * KF_STRIDE;
    float2* o1 = o0 + KF_STRIDE;
    for (int k = tid; k <= 2048; k += 512) {
        const float2 z1 = fb[SWZ(k)];
        const float2 z2 = fb[SWZ((4096 - k) & 4095)];
        o0[k] = make_float2(0.5f * (z1.x + z2.x), 0.5f * (z1.y - z2.y));
        o1[k] = make_float2(0.5f * (z1.y + z2.y), 0.5f * (z2.x - z1.x));
    }
}

// ---------------------------------------------------------------------------
// Long conv, two real rows per block: z = v1 + i*v2, filter k is REAL.
// vio layout (D, B, L): row r = d*B + b. Block blk handles rows 2blk, 2blk+1
// (same d = blk>>1, adjacent b). In place + bias.
// ---------------------------------------------------------------------------
__global__ __launch_bounds__(512) void fftconv_kernel(
    float* __restrict__ vio, const float2* __restrict__ Kf,
    const float* __restrict__ fbias)
{
    __shared__ float2 fb[4096];           // 32 KB
    const int blk = blockIdx.x;          // [0, 2048)
    const int d   = blk >> 1;
    float* v1 = vio + (size_t)(2 * blk) * LL;
    float* v2 = v1 + LL;
    const int tid = threadIdx.x;
    for (int i = tid; i < 2048; i += 512) {
        fb[SWZ(i)]        = make_float2(v1[i], v2[i]);
        fb[SWZ(i + 2048)] = make_float2(0.f, 0.f);
    }
    __syncthreads();
    fft4096_r4_ip<-1>(fb);
    const float2* kf = Kf + (size_t)d * KF_STRIDE;
    for (int i = tid; i < 4096; i += 512) {
        float2 k;
        if (i <= 2048) k = kf[i];
        else { const float2 t = kf[4096 - i]; k = make_float2(t.x, -t.y); }
        fb[SWZ(i)] = cmul(fb[SWZ(i)], k);
    }
    __syncthreads();
    fft4096_r4_ip<1>(fb);
    const float bias = fbias[d];
    for (int i = tid; i < 2048; i += 512) {
        const float2 zy = fb[SWZ(i)];
        v1[i] = zy.x + bias * v1[i];
        v2[i] = zy.y + bias * v2[i];
    }
}

// ---------------------------------------------------------------------------
// gated_bf16(B,L,D) = bf16( y(D,B,L) * x0t(D,B,L) )  -- LDS 32x32 transpose
// ---------------------------------------------------------------------------
__global__ __launch_bounds__(256) void gate_transpose_kernel(
    const float* __restrict__ y, const bf16_t* __restrict__ x0t,
    bf16_t* __restrict__ g)
{
    __shared__ float tile[32][33];
    const int b  = blockIdx.z;
    const int l0 = blockIdx.x * 32;
    const int d0 = blockIdx.y * 32;
    const int tx  = threadIdx.x & 31;
    const int tyb = threadIdx.x >> 5;    // 0..7
    #pragma unroll
    for (int i = 0; i < 4; ++i) {
        const int dy = tyb + i * 8;
        const size_t src = ((size_t)(d0 + dy) * BB + b) * LL + l0 + tx;
        tile[dy][tx] = y[src] * (float)x0t[src];
    }
    __syncthreads();
    #pragma unroll
    for (int i = 0; i < 4; ++i) {
        const int ly = tyb + i * 8;
        g[((size_t)(b * LL + l0 + ly)) * DD + d0 + tx] = (bf16_t)tile[tx][ly];
    }
}

// ---------------------------------------------------------------------------
// Launch
// ---------------------------------------------------------------------------
extern "C" void kernel_launch(void* const* d_in, const int* in_sizes, int n_in,
                              void* d_out, int out_size, void* d_ws, size_t ws_size,
                              hipStream_t stream)
{
    (void)in_sizes; (void)n_in; (void)out_size; (void)ws_size;
    const float* x   = (const float*)d_in[0];
    const float* nw0 = (const float*)d_in[1];
    const float* ipw = (const float*)d_in[2];
    const float* ipb = (const float*)d_in[3];
    const float* sfw = (const float*)d_in[4];
    const float* sfb = (const float*)d_in[5];
    const float* w1  = (const float*)d_in[6];
    const float* b1  = (const float*)d_in[7];
    const float* f1  = (const float*)d_in[8];
    const float* w2  = (const float*)d_in[9];
    const float* b2  = (const float*)d_in[10];
    const float* f2  = (const float*)d_in[11];
    const float* w3  = (const float*)d_in[12];
    const float* fbv = (const float*)d_in[13];
    const float* opw = (const float*)d_in[14];
    const float* opb = (const float*)d_in[15];
    const float* nw1 = (const float*)d_in[16];
    const float* fw1 = (const float*)d_in[17];
    const float* fb1 = (const float*)d_in[18];
    const float* fw2 = (const float*)d_in[19];
    const float* fb2 = (const float*)d_in[20];
    float* out = (float*)d_out;

    float* ws = (float*)d_ws;
    // Region 0: utb (3D, M) bf16 = 25,165,824 bf16 = 12,582,912 f. After
    // shortfilter consumes utb, the region holds:
    //   gatedb (8M bf16 @ +0), h (8M f @ +4194304)   -- both written later.
    bf16_t* utb    = (bf16_t*)ws;
    bf16_t* gatedb = (bf16_t*)ws;                       // 8,388,608 bf16
    float*  h      = ws + 4194304;                      // 8,388,608 f
    bf16_t* midb   = (bf16_t*)(ws + 12582912);          // 16,777,216 bf16
    bf16_t* xnb    = (bf16_t*)(ws + 25165824);          // 8M bf16 (also hn later)
    bf16_t* x0tb   = (bf16_t*)(ws + 29360128);          // 8,388,608 bf16 (D,B,L)
    float*  vio    = ws + 37748736;                     // 8,388,608 f (D,B,L)
    float*  kfilt  = ws + 46137344;                     // 2,097,152 f
    float2* Kf     = (float2*)(ws + 48234496);          // 1024 x KF_STRIDE cplx
    bf16_t* ipwb   = (bf16_t*)(ws + 52445184);          // 3,145,728 bf16
    bf16_t* opwb   = ipwb + 3145728;                    // 1,048,576 bf16
    bf16_t* fw1b   = opwb + 1048576;                    // 2,097,152 bf16
    bf16_t* fw2b   = fw1b + 2097152;                    // 2,097,152 bf16
    float*  h2t    = ws + 56639488;                     // (64, L) = 131,072 f
    // total: 56,770,560 f = 227.1 MB

    // 0. weight casts
    cast_bf16_kernel<<<3072*1024/1024, 256, 0, stream>>>(ipw, ipwb);
    cast_bf16_kernel<<<1024*1024/1024, 256, 0, stream>>>(opw, opwb);
    cast_bf16_kernel<<<2048*1024/1024, 256, 0, stream>>>(fw1, fw1b);
    cast_bf16_kernel<<<2048*1024/1024, 256, 0, stream>>>(fw2, fw2b);
    // 1. implicit filter: MLP phase (h2t), modulation phase (kfilt), FFT (Kf)
    filtermlp_kernel<<<LL/256, 256, 0, stream>>>(w1, b1, f1, w2, b2, f2, h2t);
    filtermod_kernel<<<dim3(LL/256, DD/32), 256, 0, stream>>>(w3, h2t, kfilt);
    kfft_kernel<<<DD/2, 512, 0, stream>>>(kfilt, Kf);
    // 2. xn = bf16(rmsnorm(x, norm_in_w))
    rmsnorm_bf16_kernel<<<MM, 256, 0, stream>>>(x, nw0, xnb);
    // 3. u_t = in_proj_w @ xn^T + b (transposed output, bf16)
    gemm_mfma_kernel<0, true, true><<<dim3(MM/128, 3072/128), 256, 0, stream>>>(
        ipwb, xnb, ipb, nullptr, nullptr, utb, 3*DD, MM, DD);
    // 4. short filter -> x0t (D,B,L) bf16, vin (D,B,L) fp32
    shortfilter_kernel<<<DD, 256, 0, stream>>>(utb, sfw, sfb, x0tb, vio);
    // 5. vio <- causal_conv(vio, k) + filter_bias * vio   (2 rows per block)
    fftconv_kernel<<<BB*DD/2, 512, 0, stream>>>(vio, Kf, fbv);
    // 6. gated_bf16(B,L,D) = y * x0
    gate_transpose_kernel<<<dim3(LL/32, DD/32, BB), 256, 0, stream>>>(vio, x0tb, gatedb);
    // 7. h = gated @ out_proj_w^T + b + x   (M=8192, N=1024, K=1024)
    gemm_mfma_kernel<1, false><<<dim3(DD/128, MM/128), 256, 0, stream>>>(
        gatedb, opwb, opb, x, h, nullptr, MM, DD, DD);
    // 8. hn = bf16(rmsnorm(h, norm_w))
    rmsnorm_bf16_kernel<<<MM, 256, 0, stream>>>(h, nw1, xnb);
    // 9. mid = bf16(gelu(hn @ ffn_w1^T + b))  (M=8192, N=2048, K=1024)
    gemm_mfma_kernel<2, true><<<dim3(2*DD/128, MM/128), 256, 0, stream>>>(
        xnb, fw1b, fb1, nullptr, nullptr, midb, MM, 2*DD, DD);
    // 10. out = mid @ ffn_w2^T + b + h      (M=8192, N=1024, K=2048)
    gemm_mfma_kernel<1, false><<<dim3(DD/128, MM/128), 256, 0, stream>>>(
        midb, fw2b, fb2, h, out, nullptr, MM, DD, 2*DD);
}

// Round 8
// 581.017 us; speedup vs baseline: 1.1893x; 1.0148x over previous
//
#include <hip/hip_runtime.h>
#include <hip/hip_bf16.h>
#include <cstddef>

// ---------------------------------------------------------------------------
// Constants for this problem: B=4, L=2048, D=1024
// ---------------------------------------------------------------------------
#define BB 4
#define LL 2048
#define DD 1024
#define MM (BB*LL)          // 8192 tokens
#define KF_STRIDE 2056      // complex elements per Kf row (>= 2049, 16B-aligned)

// LDS bank swizzle for float2 arrays: spreads Stockham write streams across
// bank-pairs. Modifies bits 2-3 only (stays in range).
#define SWZ(a) ((a) ^ (((a) >> 4) & 12))

typedef __bf16 bf16_t;
typedef __attribute__((ext_vector_type(8))) __bf16 bf16x8;
typedef __attribute__((ext_vector_type(4))) __bf16 bf16x4;
typedef __attribute__((ext_vector_type(4))) float f32x4;

// async global->LDS, 16 bytes per lane (global_load_lds_dwordx4)
#define GLD_LDS16(gp, lp) __builtin_amdgcn_global_load_lds(                 \
    (const __attribute__((address_space(1))) unsigned int*)(gp),            \
    (__attribute__((address_space(3))) unsigned int*)(lp), 16, 0, 0)

__device__ __forceinline__ float gelu_tanh(float x) {
    const float c = 0.7978845608028654f;   // sqrt(2/pi)
    float t = tanhf(c * (x + 0.044715f * x * x * x));
    return 0.5f * x * (1.0f + t);
}

__device__ __forceinline__ float2 cmul(float2 a, float2 b) {
    return make_float2(a.x * b.x - a.y * b.y, a.x * b.y + a.y * b.x);
}
__device__ __forceinline__ float2 cadd(float2 a, float2 b) {
    return make_float2(a.x + b.x, a.y + b.y);
}
__device__ __forceinline__ float2 csub(float2 a, float2 b) {
    return make_float2(a.x - b.x, a.y - b.y);
}
// multiply by i*sigma (sigma = +-1)
__device__ __forceinline__ float2 cmuli(float2 z, float s) {
    return make_float2(-s * z.y, s * z.x);
}

// ---------------------------------------------------------------------------
// fp32 -> bf16 cast of all 4 weight matrices in ONE launch.
// Regions (in 1024-element blocks): ipw 3072 | opw 1024 | fw1 2048 | fw2 2048
// ---------------------------------------------------------------------------
__global__ __launch_bounds__(256) void cast_all_kernel(
    const float* __restrict__ s0, const float* __restrict__ s1,
    const float* __restrict__ s2, const float* __restrict__ s3,
    bf16_t* __restrict__ d0, bf16_t* __restrict__ d1,
    bf16_t* __restrict__ d2, bf16_t* __restrict__ d3)
{
    const int b = blockIdx.x;
    const float* s; bf16_t* d; int base;
    if (b < 3072)      { s = s0; d = d0; base = b; }
    else if (b < 4096) { s = s1; d = d1; base = b - 3072; }
    else if (b < 6144) { s = s2; d = d2; base = b - 4096; }
    else               { s = s3; d = d3; base = b - 6144; }
    const int i = (base * 256 + threadIdx.x) * 4;
    const float4 v = *(const float4*)(s + i);
    bf16x4 o;
    o[0] = (bf16_t)v.x; o[1] = (bf16_t)v.y; o[2] = (bf16_t)v.z; o[3] = (bf16_t)v.w;
    *(bf16x4*)(d + i) = o;
}

// ---------------------------------------------------------------------------
// RMSNorm -> bf16 output: one block per row of 1024 floats
// ---------------------------------------------------------------------------
__global__ __launch_bounds__(256) void rmsnorm_bf16_kernel(
    const float* __restrict__ in, const float* __restrict__ w,
    bf16_t* __restrict__ out)
{
    const int row = blockIdx.x;
    const float4* ip = (const float4*)(in + (size_t)row * DD);
    float4 v = ip[threadIdx.x];
    float ss = v.x*v.x + v.y*v.y + v.z*v.z + v.w*v.w;
    #pragma unroll
    for (int off = 32; off > 0; off >>= 1) ss += __shfl_down(ss, off, 64);
    __shared__ float sums[4];
    const int wid = threadIdx.x >> 6;
    if ((threadIdx.x & 63) == 0) sums[wid] = ss;
    __syncthreads();
    const float tot = sums[0] + sums[1] + sums[2] + sums[3];
    const float scale = rsqrtf(tot * (1.0f / (float)DD) + 1e-8f);
    const float4 wv = ((const float4*)w)[threadIdx.x];
    bf16x4 o;
    o[0] = (bf16_t)(v.x * scale * wv.x);
    o[1] = (bf16_t)(v.y * scale * wv.y);
    o[2] = (bf16_t)(v.z * scale * wv.z);
    o[3] = (bf16_t)(v.w * scale * wv.w);
    *(bf16x4*)(out + (size_t)row * DD + threadIdx.x * 4) = o;
}

// ---------------------------------------------------------------------------
// bf16 MFMA GEMM: C(M,N) = epi(A(M,K) @ W(N,K)^T + bias) [+ res]
// 128x128 tile, BK=32, 256 thr (4 waves, 2x2), each wave 4x4 16x16x32 MFMA
// tiles, global_load_lds width=16 staging, ds_read_b128 fragments.
// EPI: 0 = bias, 1 = bias + residual, 2 = bias + tanh-GELU
// BIASROW: bias indexed by output row (for transposed-output GEMMs)
// ---------------------------------------------------------------------------
template<int EPI, bool BF16OUT, bool BIASROW = false>
__global__ __launch_bounds__(256) void gemm_mfma_kernel(
    const bf16_t* __restrict__ A,    // (M,K)
    const bf16_t* __restrict__ W,    // (N,K)
    const float* __restrict__ bias,  // (N) or (M) if BIASROW
    const float* __restrict__ res,   // (M,N) or nullptr
    float* __restrict__ Cf,          // fp32 out (if !BF16OUT)
    bf16_t* __restrict__ Cb,         // bf16 out (if BF16OUT)
    int M, int N, int K)
{
    __shared__ __align__(16) bf16_t As[128 * 32];
    __shared__ __align__(16) bf16_t Ws[128 * 32];
    const int tid  = threadIdx.x;
    const int bm   = blockIdx.y * 128;
    const int bn   = blockIdx.x * 128;
    const int lane = tid & 63;
    const int wave = tid >> 6;
    const int wr   = (wave >> 1) * 64;   // wave row offset within tile
    const int wc   = (wave & 1) * 64;    // wave col offset within tile

    const int lrow = tid >> 2;           // 0..63
    const int lcol = (tid & 3) * 8;      // 0,8,16,24 (bf16 elements)

    const bf16_t* Ag = A + (size_t)(bm + lrow) * K + lcol;
    const bf16_t* Wg = W + (size_t)(bn + lrow) * K + lcol;
    bf16_t* AsL0 = As + lrow * 32 + lcol;
    bf16_t* AsL1 = As + (64 + lrow) * 32 + lcol;
    bf16_t* WsL0 = Ws + lrow * 32 + lcol;
    bf16_t* WsL1 = Ws + (64 + lrow) * 32 + lcol;

    f32x4 acc[4][4] = {};

    const int fr = lane & 15;            // m (or n) within 16-tile
    const int fc = (lane >> 4) * 8;      // k offset (quad*8)

    for (int k0 = 0; k0 < K; k0 += 32) {
        GLD_LDS16(Ag + k0,                AsL0);
        GLD_LDS16(Ag + (size_t)64*K + k0, AsL1);
        GLD_LDS16(Wg + k0,                WsL0);
        GLD_LDS16(Wg + (size_t)64*K + k0, WsL1);
        __syncthreads();

        bf16x8 af[4], wf[4];
        #pragma unroll
        for (int i = 0; i < 4; ++i)
            af[i] = *(const bf16x8*)(As + (wr + i*16 + fr) * 32 + fc);
        #pragma unroll
        for (int j = 0; j < 4; ++j)
            wf[j] = *(const bf16x8*)(Ws + (wc + j*16 + fr) * 32 + fc);
        #pragma unroll
        for (int i = 0; i < 4; ++i)
            #pragma unroll
            for (int j = 0; j < 4; ++j)
                acc[i][j] = __builtin_amdgcn_mfma_f32_16x16x32_bf16(
                    af[i], wf[j], acc[i][j], 0, 0, 0);
        __syncthreads();
    }

    // Epilogue. C/D layout: col = lane&15, row = (lane>>4)*4 + reg
    const int fq = lane >> 4;
    #pragma unroll
    for (int i = 0; i < 4; ++i) {
        const int row0 = bm + wr + i*16 + fq*4;
        #pragma unroll
        for (int j = 0; j < 4; ++j) {
            const int col = bn + wc + j*16 + fr;
            const float bcol = BIASROW ? 0.0f : bias[col];
            #pragma unroll
            for (int r = 0; r < 4; ++r) {
                float v = acc[i][j][r] + (BIASROW ? bias[row0 + r] : bcol);
                if constexpr (EPI == 2) v = gelu_tanh(v);
                if constexpr (EPI == 1) v += res[(size_t)(row0 + r) * N + col];
                if constexpr (BF16OUT)
                    Cb[(size_t)(row0 + r) * N + col] = (bf16_t)v;
                else
                    Cf[(size_t)(row0 + r) * N + col] = v;
            }
        }
    }
}

// ---------------------------------------------------------------------------
// Depthwise causal k=3 short filter on u_t (3D, M) channel-major bf16:
//   x0t (D, M) bf16  (layout (D,B,L)) = conv channels [0,D)
//   vin (D, M) fp32  (layout (D,B,L)) = conv[2D..3D) * conv[D..2D)
// One block per d; fully coalesced reads and writes, no LDS.
// ---------------------------------------------------------------------------
__global__ __launch_bounds__(256) void shortfilter_kernel(
    const bf16_t* __restrict__ ut, const float* __restrict__ sw,
    const float* __restrict__ sb, bf16_t* __restrict__ x0t,
    float* __restrict__ vin)
{
    const int d = blockIdx.x;             // 0..1023
    const int c0 = d, c1 = DD + d, c2 = 2 * DD + d;
    const float w0a = sw[c0*3+0], w0b = sw[c0*3+1], w0c = sw[c0*3+2], b0 = sb[c0];
    const float w1a = sw[c1*3+0], w1b = sw[c1*3+1], w1c = sw[c1*3+2], b1 = sb[c1];
    const float w2a = sw[c2*3+0], w2b = sw[c2*3+1], w2c = sw[c2*3+2], b2 = sb[c2];
    const bf16_t* r0 = ut + (size_t)c0 * MM;
    const bf16_t* r1 = ut + (size_t)c1 * MM;
    const bf16_t* r2 = ut + (size_t)c2 * MM;
    bf16_t* o0 = x0t + (size_t)d * MM;
    float*  o1 = vin + (size_t)d * MM;
    for (int m = threadIdx.x; m < MM; m += 256) {
        const int l = m & (LL - 1);
        float v0 = w0c * (float)r0[m] + b0;
        float v1 = w1c * (float)r1[m] + b1;
        float v2 = w2c * (float)r2[m] + b2;
        if (l >= 1) {
            v0 += w0b * (float)r0[m-1];
            v1 += w1b * (float)r1[m-1];
            v2 += w2b * (float)r2[m-1];
        }
        if (l >= 2) {
            v0 += w0a * (float)r0[m-2];
            v1 += w1a * (float)r1[m-2];
            v2 += w2a * (float)r2[m-2];
        }
        o0[m] = (bf16_t)v0;
        o1[m] = v2 * v1;
    }
}

// ---------------------------------------------------------------------------
// Implicit filter MLP, phase 1: h2t (64, L). One thread per position l.
// w2 staged in LDS (broadcast reads); h1 in registers (FULLY static indexing
// -- partial unroll spills to scratch, R5 lesson); coalesced h2t stores.
// ---------------------------------------------------------------------------
__global__ __launch_bounds__(256) void filtermlp_kernel(
    const float* __restrict__ w1, const float* __restrict__ b1,
    const float* __restrict__ f1, const float* __restrict__ w2,
    const float* __restrict__ b2, const float* __restrict__ f2,
    float* __restrict__ h2t)
{
    __shared__ float w2s[64 * 64];      // 16 KB
    for (int i = threadIdx.x; i < 64 * 64; i += 256) w2s[i] = w2[i];
    __syncthreads();
    const int l = blockIdx.x * 256 + threadIdx.x;   // 0..2047
    const float t = (float)l / (float)(LL - 1);
    const float ang = 1e-4f * 6.283185307179586f * (float)l / (float)LL;
    const float z0 = t, z1 = cosf(ang), z2 = -sinf(ang);
    float h1[64];
    #pragma unroll
    for (int j = 0; j < 64; ++j) {
        const float s = w1[j*3+0]*z0 + w1[j*3+1]*z1 + w1[j*3+2]*z2 + b1[j];
        h1[j] = sinf(f1[j] * s);
    }
    for (int j = 0; j < 64; ++j) {
        float s = b2[j];
        #pragma unroll   // FULL unroll: h1[jj] must be compile-time indexed
        for (int jj = 0; jj < 64; ++jj) s += w2s[j*64 + jj] * h1[jj];
        h2t[j * LL + l] = sinf(f2[j] * s);
    }
}

// ---------------------------------------------------------------------------
// Implicit filter, phase 2: kfilt[d][l] = (w3[d,:] . h2t[:,l]) * exp(-t|delta_d|)
// Tile: 32 d x 256 l per block. w3 tile in LDS (broadcast), h2t coalesced.
// ---------------------------------------------------------------------------
__global__ __launch_bounds__(256) void filtermod_kernel(
    const float* __restrict__ w3, const float* __restrict__ h2t,
    float* __restrict__ kfilt)
{
    __shared__ float w3s[32 * 64];      // 8 KB
    const int d0 = blockIdx.y * 32;
    const int l  = blockIdx.x * 256 + threadIdx.x;
    for (int i = threadIdx.x; i < 32 * 64; i += 256) w3s[i] = w3[d0 * 64 + i];
    __syncthreads();
    float acc[32] = {};
    for (int j = 0; j < 64; ++j) {
        const float v = h2t[j * LL + l];
        #pragma unroll
        for (int dd = 0; dd < 32; ++dd) acc[dd] += w3s[dd*64 + j] * v;
    }
    const float t = (float)l / (float)(LL - 1);
    const float min_decay = -3.0701134573253944f;   // ln(1e-2)/1.5
    const float max_decay = -15.350567286626972f;   // ln(1e-2)/0.3
    #pragma unroll
    for (int dd = 0; dd < 32; ++dd) {
        const int d = d0 + dd;
        const float delta = fabsf(min_decay + (max_decay - min_decay) * (float)d / (float)(DD - 1));
        kfilt[(size_t)d * LL + l] = acc[dd] * expf(-t * delta);
    }
}

// ---------------------------------------------------------------------------
// 4096-point complex Stockham RADIX-8 FFT, in-place in 32 KB LDS.
// 4 stages (4096 = 8^4), 512 threads, one 8-point butterfly per thread per
// stage (read-all / barrier / write-all: each element read+written by
// exactly one thread per stage -> race-free).
// General Stockham radix-r rule (derived from the verified radix-2/4 forms):
//   reads  a_k = buf[idx + k*4096/r],  idx in [0,4096/r)
//   p = idx>>ls, q = idx & (2^ls - 1), W = e^{i*sign*2pi*p/(4096>>ls)}
//   writes buf[q + (p<<(ls+log2 r)) + m*2^ls] = W^m * DFT_r(a)[m]
// with DFT_r sign convention e^{sign*2pi*i*k*m/r}.
// SIGN = -1 forward, +1 unnormalized inverse. Ends with __syncthreads().
// ---------------------------------------------------------------------------
template<int SIGN>
__device__ __forceinline__ void fft4096_r8_ip(float2* __restrict__ buf)
{
    const float fs = (float)SIGN;
    const float RH = 0.7071067811865476f;   // sqrt(2)/2
    const int tid = threadIdx.x;            // 0..511
    #pragma unroll
    for (int t = 0; t < 4; ++t) {
        const int ls = 3 * t;               // log2(stride): 0,3,6,9
        const int s  = 1 << ls;
        const float theta = fs * 6.283185307179586f / (float)(4096 >> ls);
        float2 a[8];
        #pragma unroll
        for (int m = 0; m < 8; ++m) a[m] = buf[SWZ(tid + m * 512)];
        __syncthreads();
        const int p = tid >> ls;
        const int q = tid & (s - 1);
        float sn, cs;
        __sincosf(theta * (float)p, &sn, &cs);
        const float2 W1 = make_float2(cs, sn);
        const float2 W2 = cmul(W1, W1);
        const float2 W3 = cmul(W2, W1);
        const float2 W4 = cmul(W2, W2);
        const float2 W5 = cmul(W4, W1);
        const float2 W6 = cmul(W4, W2);
        const float2 W7 = cmul(W4, W3);
        // DFT4 of evens (a0,a2,a4,a6) and odds (a1,a3,a5,a7)
        const float2 es = cadd(a[0], a[4]), ed = csub(a[0], a[4]);
        const float2 fs2 = cadd(a[2], a[6]), fd = csub(a[2], a[6]);
        const float2 E0 = cadd(es, fs2);
        const float2 E1 = cadd(ed, cmuli(fd, fs));
        const float2 E2 = csub(es, fs2);
        const float2 E3 = csub(ed, cmuli(fd, fs));
        const float2 os = cadd(a[1], a[5]), od = csub(a[1], a[5]);
        const float2 gs = cadd(a[3], a[7]), gd = csub(a[3], a[7]);
        const float2 O0 = cadd(os, gs);
        const float2 O1 = cadd(od, cmuli(gd, fs));
        const float2 O2 = csub(os, gs);
        const float2 O3 = csub(od, cmuli(gd, fs));
        // T_m = w8^m * O_m  (w8 = e^{i*sign*pi/4})
        const float2 T0 = O0;
        const float2 T1 = make_float2(RH * (O1.x - fs * O1.y), RH * (fs * O1.x + O1.y));
        const float2 T2 = cmuli(O2, fs);
        const float2 T3 = make_float2(RH * (-O3.x - fs * O3.y), RH * (fs * O3.x - O3.y));
        const int o = q + (p << (ls + 3));
        buf[SWZ(o)]         = cadd(E0, T0);
        buf[SWZ(o + s)]     = cmul(W1, cadd(E1, T1));
        buf[SWZ(o + 2*s)]   = cmul(W2, cadd(E2, T2));
        buf[SWZ(o + 3*s)]   = cmul(W3, cadd(E3, T3));
        buf[SWZ(o + 4*s)]   = cmul(W4, csub(E0, T0));
        buf[SWZ(o + 5*s)]   = cmul(W5, csub(E1, T1));
        buf[SWZ(o + 6*s)]   = cmul(W6, csub(E2, T2));
        buf[SWZ(o + 7*s)]   = cmul(W7, csub(E3, T3));
        __syncthreads();
    }
}

// ---------------------------------------------------------------------------
// FFT of filter rows, two real rows per block (z = k_{2d} + i*k_{2d+1}).
// Half-spectra extracted via conjugate symmetry; /4096 folded in.
// ---------------------------------------------------------------------------
__global__ __launch_bounds__(512, 4) void kfft_kernel(
    const float* __restrict__ kfilt, float2* __restrict__ Kf)
{
    __shared__ float2 fb[4096];           // 32 KB
    const int d0 = blockIdx.x * 2;
    const float* k0 = kfilt + (size_t)d0 * LL;
    const float* k1 = k0 + LL;
    const float inv = 1.0f / 4096.0f;
    const int tid = threadIdx.x;
    for (int i = tid; i < 2048; i += 512) {
        fb[SWZ(i)]        = make_float2(k0[i] * inv, k1[i] * inv);
        fb[SWZ(i + 2048)] = make_float2(0.f, 0.f);
    }
    __syncthreads();
    fft4096_r8_ip<-1>(fb);
    float2* o0 = Kf + (size_t)d0 * KF_STRIDE;
    float2* o1 = o0 + KF_STRIDE;
    for (int k = tid; k <= 2048; k += 512) {
        const float2 z1 = fb[SWZ(k)];
        const float2 z2 = fb[SWZ((4096 - k) & 4095)];
        o0[k] = make_float2(0.5f * (z1.x + z2.x), 0.5f * (z1.y - z2.y));
        o1[k] = make_float2(0.5f * (z1.y + z2.y), 0.5f * (z2.x - z1.x));
    }
}

// ---------------------------------------------------------------------------
// Long conv, two real rows per block: z = v1 + i*v2, filter k is REAL.
// vio layout (D, B, L): row r = d*B + b. Block blk handles rows 2blk, 2blk+1
// (same d = blk>>1, adjacent b). In place + bias.
// ---------------------------------------------------------------------------
__global__ __launch_bounds__(512, 4) void fftconv_kernel(
    float* __restrict__ vio, const float2* __restrict__ Kf,
    const float* __restrict__ fbias)
{
    __shared__ float2 fb[4096];           // 32 KB
    const int blk = blockIdx.x;          // [0, 2048)
    const int d   = blk >> 1;
    float* v1 = vio + (size_t)(2 * blk) * LL;
    float* v2 = v1 + LL;
    const int tid = threadIdx.x;
    for (int i = tid; i < 2048; i += 512) {
        fb[SWZ(i)]        = make_float2(v1[i], v2[i]);
        fb[SWZ(i + 2048)] = make_float2(0.f, 0.f);
    }
    __syncthreads();
    fft4096_r8_ip<-1>(fb);
    const float2* kf = Kf + (size_t)d * KF_STRIDE;
    for (int i = tid; i < 4096; i += 512) {
        float2 k;
        if (i <= 2048) k = kf[i];
        else { const float2 t = kf[4096 - i]; k = make_float2(t.x, -t.y); }
        fb[SWZ(i)] = cmul(fb[SWZ(i)], k);
    }
    __syncthreads();
    fft4096_r8_ip<1>(fb);
    const float bias = fbias[d];
    for (int i = tid; i < 2048; i += 512) {
        const float2 zy = fb[SWZ(i)];
        v1[i] = zy.x + bias * v1[i];
        v2[i] = zy.y + bias * v2[i];
    }
}

// ---------------------------------------------------------------------------
// gated_bf16(B,L,D) = bf16( y(D,B,L) * x0t(D,B,L) )  -- LDS 32x32 transpose
// ---------------------------------------------------------------------------
__global__ __launch_bounds__(256) void gate_transpose_kernel(
    const float* __restrict__ y, const bf16_t* __restrict__ x0t,
    bf16_t* __restrict__ g)
{
    __shared__ float tile[32][33];
    const int b  = blockIdx.z;
    const int l0 = blockIdx.x * 32;
    const int d0 = blockIdx.y * 32;
    const int tx  = threadIdx.x & 31;
    const int tyb = threadIdx.x >> 5;    // 0..7
    #pragma unroll
    for (int i = 0; i < 4; ++i) {
        const int dy = tyb + i * 8;
        const size_t src = ((size_t)(d0 + dy) * BB + b) * LL + l0 + tx;
        tile[dy][tx] = y[src] * (float)x0t[src];
    }
    __syncthreads();
    #pragma unroll
    for (int i = 0; i < 4; ++i) {
        const int ly = tyb + i * 8;
        g[((size_t)(b * LL + l0 + ly)) * DD + d0 + tx] = (bf16_t)tile[tx][ly];
    }
}

// ---------------------------------------------------------------------------
// Launch
// ---------------------------------------------------------------------------
extern "C" void kernel_launch(void* const* d_in, const int* in_sizes, int n_in,
                              void* d_out, int out_size, void* d_ws, size_t ws_size,
                              hipStream_t stream)
{
    (void)in_sizes; (void)n_in; (void)out_size; (void)ws_size;
    const float* x   = (const float*)d_in[0];
    const float* nw0 = (const float*)d_in[1];
    const float* ipw = (const float*)d_in[2];
    const float* ipb = (const float*)d_in[3];
    const float* sfw = (const float*)d_in[4];
    const float* sfb = (const float*)d_in[5];
    const float* w1  = (const float*)d_in[6];
    const float* b1  = (const float*)d_in[7];
    const float* f1  = (const float*)d_in[8];
    const float* w2  = (const float*)d_in[9];
    const float* b2  = (const float*)d_in[10];
    const float* f2  = (const float*)d_in[11];
    const float* w3  = (const float*)d_in[12];
    const float* fbv = (const float*)d_in[13];
    const float* opw = (const float*)d_in[14];
    const float* opb = (const float*)d_in[15];
    const float* nw1 = (const float*)d_in[16];
    const float* fw1 = (const float*)d_in[17];
    const float* fb1 = (const float*)d_in[18];
    const float* fw2 = (const float*)d_in[19];
    const float* fb2 = (const float*)d_in[20];
    float* out = (float*)d_out;

    float* ws = (float*)d_ws;
    // Region 0: utb (3D, M) bf16 = 25,165,824 bf16 = 12,582,912 f. After
    // shortfilter consumes utb, the region holds:
    //   gatedb (8M bf16 @ +0), h (8M f @ +4194304)   -- both written later.
    bf16_t* utb    = (bf16_t*)ws;
    bf16_t* gatedb = (bf16_t*)ws;                       // 8,388,608 bf16
    float*  h      = ws + 4194304;                      // 8,388,608 f
    bf16_t* midb   = (bf16_t*)(ws + 12582912);          // 16,777,216 bf16
    bf16_t* xnb    = (bf16_t*)(ws + 25165824);          // 8M bf16 (also hn later)
    bf16_t* x0tb   = (bf16_t*)(ws + 29360128);          // 8,388,608 bf16 (D,B,L)
    float*  vio    = ws + 37748736;                     // 8,388,608 f (D,B,L)
    float*  kfilt  = ws + 46137344;                     // 2,097,152 f
    float2* Kf     = (float2*)(ws + 48234496);          // 1024 x KF_STRIDE cplx
    bf16_t* ipwb   = (bf16_t*)(ws + 52445184);          // 3,145,728 bf16
    bf16_t* opwb   = ipwb + 3145728;                    // 1,048,576 bf16
    bf16_t* fw1b   = opwb + 1048576;                    // 2,097,152 bf16
    bf16_t* fw2b   = fw1b + 2097152;                    // 2,097,152 bf16
    float*  h2t    = ws + 56639488;                     // (64, L) = 131,072 f
    // total: 56,770,560 f = 227.1 MB

    // 0. weight casts (single launch, region-dispatched)
    cast_all_kernel<<<8192, 256, 0, stream>>>(ipw, opw, fw1, fw2,
                                              ipwb, opwb, fw1b, fw2b);
    // 1. implicit filter: MLP phase (h2t), modulation phase (kfilt), FFT (Kf)
    filtermlp_kernel<<<LL/256, 256, 0, stream>>>(w1, b1, f1, w2, b2, f2, h2t);
    filtermod_kernel<<<dim3(LL/256, DD/32), 256, 0, stream>>>(w3, h2t, kfilt);
    kfft_kernel<<<DD/2, 512, 0, stream>>>(kfilt, Kf);
    // 2. xn = bf16(rmsnorm(x, norm_in_w))
    rmsnorm_bf16_kernel<<<MM, 256, 0, stream>>>(x, nw0, xnb);
    // 3. u_t = in_proj_w @ xn^T + b (transposed output, bf16)
    gemm_mfma_kernel<0, true, true><<<dim3(MM/128, 3072/128), 256, 0, stream>>>(
        ipwb, xnb, ipb, nullptr, nullptr, utb, 3*DD, MM, DD);
    // 4. short filter -> x0t (D,B,L) bf16, vin (D,B,L) fp32
    shortfilter_kernel<<<DD, 256, 0, stream>>>(utb, sfw, sfb, x0tb, vio);
    // 5. vio <- causal_conv(vio, k) + filter_bias * vio   (2 rows per block)
    fftconv_kernel<<<BB*DD/2, 512, 0, stream>>>(vio, Kf, fbv);
    // 6. gated_bf16(B,L,D) = y * x0
    gate_transpose_kernel<<<dim3(LL/32, DD/32, BB), 256, 0, stream>>>(vio, x0tb, gatedb);
    // 7. h = gated @ out_proj_w^T + b + x   (M=8192, N=1024, K=1024)
    gemm_mfma_kernel<1, false><<<dim3(DD/128, MM/128), 256, 0, stream>>>(
        gatedb, opwb, opb, x, h, nullptr, MM, DD, DD);
    // 8. hn = bf16(rmsnorm(h, norm_w))
    rmsnorm_bf16_kernel<<<MM, 256, 0, stream>>>(h, nw1, xnb);
    // 9. mid = bf16(gelu(hn @ ffn_w1^T + b))  (M=8192, N=2048, K=1024)
    gemm_mfma_kernel<2, true><<<dim3(2*DD/128, MM/128), 256, 0, stream>>>(
        xnb, fw1b, fb1, nullptr, nullptr, midb, MM, 2*DD, DD);
    // 10. out = mid @ ffn_w2^T + b + h      (M=8192, N=1024, K=2048)
    gemm_mfma_kernel<1, false><<<dim3(DD/128, MM/128), 256, 0, stream>>>(
        midb, fw2b, fb2, h, out, nullptr, MM, DD, 2*DD);
}

// Round 9
// 543.963 us; speedup vs baseline: 1.2703x; 1.0681x over previous
//
#include <hip/hip_runtime.h>
#include <hip/hip_bf16.h>
#include <cstddef>

// ---------------------------------------------------------------------------
// Constants for this problem: B=4, L=2048, D=1024
// ---------------------------------------------------------------------------
#define BB 4
#define LL 2048
#define DD 1024
#define MM (BB*LL)          // 8192 tokens
#define KF_STRIDE 2056      // complex elements per Kf row (>= 2049, 16B-aligned)

// LDS bank swizzle for float2 arrays: spreads Stockham write streams across
// bank-pairs. Modifies bits 2-3 only (stays in range).
#define SWZ(a) ((a) ^ (((a) >> 4) & 12))

typedef __bf16 bf16_t;
typedef __attribute__((ext_vector_type(8))) __bf16 bf16x8;
typedef __attribute__((ext_vector_type(4))) __bf16 bf16x4;
typedef __attribute__((ext_vector_type(4))) float f32x4;

// async global->LDS, 16 bytes per lane (global_load_lds_dwordx4)
#define GLD_LDS16(gp, lp) __builtin_amdgcn_global_load_lds(                 \
    (const __attribute__((address_space(1))) unsigned int*)(gp),            \
    (__attribute__((address_space(3))) unsigned int*)(lp), 16, 0, 0)

__device__ __forceinline__ float gelu_tanh(float x) {
    const float c = 0.7978845608028654f;   // sqrt(2/pi)
    float t = tanhf(c * (x + 0.044715f * x * x * x));
    return 0.5f * x * (1.0f + t);
}

__device__ __forceinline__ float2 cmul(float2 a, float2 b) {
    return make_float2(a.x * b.x - a.y * b.y, a.x * b.y + a.y * b.x);
}
__device__ __forceinline__ float2 cadd(float2 a, float2 b) {
    return make_float2(a.x + b.x, a.y + b.y);
}
__device__ __forceinline__ float2 csub(float2 a, float2 b) {
    return make_float2(a.x - b.x, a.y - b.y);
}
// multiply by i*sigma (sigma = +-1)
__device__ __forceinline__ float2 cmuli(float2 z, float s) {
    return make_float2(-s * z.y, s * z.x);
}

// ---------------------------------------------------------------------------
// fp32 -> bf16 cast of all 4 weight matrices in ONE launch.
// Regions (in 1024-element blocks): ipw 3072 | opw 1024 | fw1 2048 | fw2 2048
// ---------------------------------------------------------------------------
__global__ __launch_bounds__(256) void cast_all_kernel(
    const float* __restrict__ s0, const float* __restrict__ s1,
    const float* __restrict__ s2, const float* __restrict__ s3,
    bf16_t* __restrict__ d0, bf16_t* __restrict__ d1,
    bf16_t* __restrict__ d2, bf16_t* __restrict__ d3)
{
    const int b = blockIdx.x;
    const float* s; bf16_t* d; int base;
    if (b < 3072)      { s = s0; d = d0; base = b; }
    else if (b < 4096) { s = s1; d = d1; base = b - 3072; }
    else if (b < 6144) { s = s2; d = d2; base = b - 4096; }
    else               { s = s3; d = d3; base = b - 6144; }
    const int i = (base * 256 + threadIdx.x) * 4;
    const float4 v = *(const float4*)(s + i);
    bf16x4 o;
    o[0] = (bf16_t)v.x; o[1] = (bf16_t)v.y; o[2] = (bf16_t)v.z; o[3] = (bf16_t)v.w;
    *(bf16x4*)(d + i) = o;
}

// ---------------------------------------------------------------------------
// RMSNorm -> bf16 output: one block per row of 1024 floats
// ---------------------------------------------------------------------------
__global__ __launch_bounds__(256) void rmsnorm_bf16_kernel(
    const float* __restrict__ in, const float* __restrict__ w,
    bf16_t* __restrict__ out)
{
    const int row = blockIdx.x;
    const float4* ip = (const float4*)(in + (size_t)row * DD);
    float4 v = ip[threadIdx.x];
    float ss = v.x*v.x + v.y*v.y + v.z*v.z + v.w*v.w;
    #pragma unroll
    for (int off = 32; off > 0; off >>= 1) ss += __shfl_down(ss, off, 64);
    __shared__ float sums[4];
    const int wid = threadIdx.x >> 6;
    if ((threadIdx.x & 63) == 0) sums[wid] = ss;
    __syncthreads();
    const float tot = sums[0] + sums[1] + sums[2] + sums[3];
    const float scale = rsqrtf(tot * (1.0f / (float)DD) + 1e-8f);
    const float4 wv = ((const float4*)w)[threadIdx.x];
    bf16x4 o;
    o[0] = (bf16_t)(v.x * scale * wv.x);
    o[1] = (bf16_t)(v.y * scale * wv.y);
    o[2] = (bf16_t)(v.z * scale * wv.z);
    o[3] = (bf16_t)(v.w * scale * wv.w);
    *(bf16x4*)(out + (size_t)row * DD + threadIdx.x * 4) = o;
}

// ---------------------------------------------------------------------------
// bf16 MFMA GEMM: C(M,N) = epi(A(M,K) @ W(N,K)^T + bias) [+ res]
// 128x128 tile, BK=64 (32 KB LDS), 256 thr (4 waves, 2x2), each wave 4x4
// 16x16x32 MFMA tiles (x2 k-subs per LDS tile).
// LDS chunk swizzle: 16-B chunk (row, q) stored at chunk pos row*8 + (q^(row&7)).
// global_load_lds fixes LDS pos = c*256+tid, so the GLOBAL chunk loaded is
// q = (p&7) ^ (row&7); fragment ds_reads apply the same XOR -> bank-uniform
// (2 lanes/bank = free), kills the 8-way conflicts measured in R8 (6.29M cyc).
// EPI: 0 = bias, 1 = bias + residual, 2 = bias + tanh-GELU
// BIASROW: bias indexed by output row (for transposed-output GEMMs)
// ---------------------------------------------------------------------------
template<int EPI, bool BF16OUT, bool BIASROW = false>
__global__ __launch_bounds__(256) void gemm_mfma_kernel(
    const bf16_t* __restrict__ A,    // (M,K)
    const bf16_t* __restrict__ W,    // (N,K)
    const float* __restrict__ bias,  // (N) or (M) if BIASROW
    const float* __restrict__ res,   // (M,N) or nullptr
    float* __restrict__ Cf,          // fp32 out (if !BF16OUT)
    bf16_t* __restrict__ Cb,         // bf16 out (if BF16OUT)
    int M, int N, int K)
{
    __shared__ __align__(16) bf16_t As[128 * 64];   // 16 KB
    __shared__ __align__(16) bf16_t Ws[128 * 64];   // 16 KB
    const int tid  = threadIdx.x;
    const int bm   = blockIdx.y * 128;
    const int bn   = blockIdx.x * 128;
    const int lane = tid & 63;
    const int wave = tid >> 6;
    const int wr   = (wave >> 1) * 64;   // wave row offset within tile
    const int wc   = (wave & 1) * 64;    // wave col offset within tile

    // staging: LDS chunk position p = c*256 + tid -> row = p>>3, qlds = p&7,
    // global chunk q = qlds ^ (row&7)  (element offset = q*8)
    int srow[4], sqg[4];
    #pragma unroll
    for (int c = 0; c < 4; ++c) {
        const int p = c * 256 + tid;
        srow[c] = p >> 3;
        sqg[c]  = (((p & 7) ^ (srow[c] & 7)) << 3);
    }

    f32x4 acc[4][4] = {};

    const int fr = lane & 15;            // m (or n) within 16-tile
    const int fc = (lane >> 4) * 8;      // k offset within 32 (quad*8)

    for (int k0 = 0; k0 < K; k0 += 64) {
        #pragma unroll
        for (int c = 0; c < 4; ++c) {
            GLD_LDS16(A + (size_t)(bm + srow[c]) * K + k0 + sqg[c],
                      As + c * 2048 + tid * 8);
            GLD_LDS16(W + (size_t)(bn + srow[c]) * K + k0 + sqg[c],
                      Ws + c * 2048 + tid * 8);
        }
        __syncthreads();

        #pragma unroll
        for (int ks = 0; ks < 64; ks += 32) {
            const int q = (ks + fc) >> 3;
            bf16x8 af[4], wf[4];
            #pragma unroll
            for (int i = 0; i < 4; ++i) {
                const int r = wr + i*16 + fr;
                af[i] = *(const bf16x8*)(As + r * 64 + ((q ^ (r & 7)) << 3));
            }
            #pragma unroll
            for (int j = 0; j < 4; ++j) {
                const int r = wc + j*16 + fr;
                wf[j] = *(const bf16x8*)(Ws + r * 64 + ((q ^ (r & 7)) << 3));
            }
            #pragma unroll
            for (int i = 0; i < 4; ++i)
                #pragma unroll
                for (int j = 0; j < 4; ++j)
                    acc[i][j] = __builtin_amdgcn_mfma_f32_16x16x32_bf16(
                        af[i], wf[j], acc[i][j], 0, 0, 0);
        }
        __syncthreads();
    }

    // Epilogue. C/D layout: col = lane&15, row = (lane>>4)*4 + reg
    const int fq = lane >> 4;
    #pragma unroll
    for (int i = 0; i < 4; ++i) {
        const int row0 = bm + wr + i*16 + fq*4;
        #pragma unroll
        for (int j = 0; j < 4; ++j) {
            const int col = bn + wc + j*16 + fr;
            const float bcol = BIASROW ? 0.0f : bias[col];
            #pragma unroll
            for (int r = 0; r < 4; ++r) {
                float v = acc[i][j][r] + (BIASROW ? bias[row0 + r] : bcol);
                if constexpr (EPI == 2) v = gelu_tanh(v);
                if constexpr (EPI == 1) v += res[(size_t)(row0 + r) * N + col];
                if constexpr (BF16OUT)
                    Cb[(size_t)(row0 + r) * N + col] = (bf16_t)v;
                else
                    Cf[(size_t)(row0 + r) * N + col] = v;
            }
        }
    }
}

// ---------------------------------------------------------------------------
// Depthwise causal k=3 short filter on u_t (3D, M) channel-major bf16:
//   x0t (D, M) bf16  (layout (D,B,L)) = conv channels [0,D)
//   vin (D, M) fp32  (layout (D,B,L)) = conv[2D..3D) * conv[D..2D)
// One block per d; fully coalesced reads and writes, no LDS.
// ---------------------------------------------------------------------------
__global__ __launch_bounds__(256) void shortfilter_kernel(
    const bf16_t* __restrict__ ut, const float* __restrict__ sw,
    const float* __restrict__ sb, bf16_t* __restrict__ x0t,
    float* __restrict__ vin)
{
    const int d = blockIdx.x;             // 0..1023
    const int c0 = d, c1 = DD + d, c2 = 2 * DD + d;
    const float w0a = sw[c0*3+0], w0b = sw[c0*3+1], w0c = sw[c0*3+2], b0 = sb[c0];
    const float w1a = sw[c1*3+0], w1b = sw[c1*3+1], w1c = sw[c1*3+2], b1 = sb[c1];
    const float w2a = sw[c2*3+0], w2b = sw[c2*3+1], w2c = sw[c2*3+2], b2 = sb[c2];
    const bf16_t* r0 = ut + (size_t)c0 * MM;
    const bf16_t* r1 = ut + (size_t)c1 * MM;
    const bf16_t* r2 = ut + (size_t)c2 * MM;
    bf16_t* o0 = x0t + (size_t)d * MM;
    float*  o1 = vin + (size_t)d * MM;
    for (int m = threadIdx.x; m < MM; m += 256) {
        const int l = m & (LL - 1);
        float v0 = w0c * (float)r0[m] + b0;
        float v1 = w1c * (float)r1[m] + b1;
        float v2 = w2c * (float)r2[m] + b2;
        if (l >= 1) {
            v0 += w0b * (float)r0[m-1];
            v1 += w1b * (float)r1[m-1];
            v2 += w2b * (float)r2[m-1];
        }
        if (l >= 2) {
            v0 += w0a * (float)r0[m-2];
            v1 += w1a * (float)r1[m-2];
            v2 += w2a * (float)r2[m-2];
        }
        o0[m] = (bf16_t)v0;
        o1[m] = v2 * v1;
    }
}

// ---------------------------------------------------------------------------
// Implicit filter MLP, phase 1: h2t (64, L). One thread per position l.
// w2 staged in LDS (broadcast reads); h1 in registers (FULLY static indexing
// -- partial unroll spills to scratch, R5 lesson); coalesced h2t stores.
// ---------------------------------------------------------------------------
__global__ __launch_bounds__(256) void filtermlp_kernel(
    const float* __restrict__ w1, const float* __restrict__ b1,
    const float* __restrict__ f1, const float* __restrict__ w2,
    const float* __restrict__ b2, const float* __restrict__ f2,
    float* __restrict__ h2t)
{
    __shared__ float w2s[64 * 64];      // 16 KB
    for (int i = threadIdx.x; i < 64 * 64; i += 256) w2s[i] = w2[i];
    __syncthreads();
    const int l = blockIdx.x * 256 + threadIdx.x;   // 0..2047
    const float t = (float)l / (float)(LL - 1);
    const float ang = 1e-4f * 6.283185307179586f * (float)l / (float)LL;
    const float z0 = t, z1 = cosf(ang), z2 = -sinf(ang);
    float h1[64];
    #pragma unroll
    for (int j = 0; j < 64; ++j) {
        const float s = w1[j*3+0]*z0 + w1[j*3+1]*z1 + w1[j*3+2]*z2 + b1[j];
        h1[j] = sinf(f1[j] * s);
    }
    for (int j = 0; j < 64; ++j) {
        float s = b2[j];
        #pragma unroll   // FULL unroll: h1[jj] must be compile-time indexed
        for (int jj = 0; jj < 64; ++jj) s += w2s[j*64 + jj] * h1[jj];
        h2t[j * LL + l] = sinf(f2[j] * s);
    }
}

// ---------------------------------------------------------------------------
// Implicit filter, phase 2: kfilt[d][l] = (w3[d,:] . h2t[:,l]) * exp(-t|delta_d|)
// Tile: 32 d x 256 l per block. w3 tile in LDS (broadcast), h2t coalesced.
// ---------------------------------------------------------------------------
__global__ __launch_bounds__(256) void filtermod_kernel(
    const float* __restrict__ w3, const float* __restrict__ h2t,
    float* __restrict__ kfilt)
{
    __shared__ float w3s[32 * 64];      // 8 KB
    const int d0 = blockIdx.y * 32;
    const int l  = blockIdx.x * 256 + threadIdx.x;
    for (int i = threadIdx.x; i < 32 * 64; i += 256) w3s[i] = w3[d0 * 64 + i];
    __syncthreads();
    float acc[32] = {};
    for (int j = 0; j < 64; ++j) {
        const float v = h2t[j * LL + l];
        #pragma unroll
        for (int dd = 0; dd < 32; ++dd) acc[dd] += w3s[dd*64 + j] * v;
    }
    const float t = (float)l / (float)(LL - 1);
    const float min_decay = -3.0701134573253944f;   // ln(1e-2)/1.5
    const float max_decay = -15.350567286626972f;   // ln(1e-2)/0.3
    #pragma unroll
    for (int dd = 0; dd < 32; ++dd) {
        const int d = d0 + dd;
        const float delta = fabsf(min_decay + (max_decay - min_decay) * (float)d / (float)(DD - 1));
        kfilt[(size_t)d * LL + l] = acc[dd] * expf(-t * delta);
    }
}

// ---------------------------------------------------------------------------
// 4096-point complex Stockham RADIX-8 FFT, in-place in 32 KB LDS.
// 4 stages (4096 = 8^4), 512 threads, one 8-point butterfly per thread per
// stage (read-all / barrier / write-all: race-free).
// SIGN = -1 forward, +1 unnormalized inverse. Ends with __syncthreads().
// ---------------------------------------------------------------------------
template<int SIGN>
__device__ __forceinline__ void fft4096_r8_ip(float2* __restrict__ buf)
{
    const float fs = (float)SIGN;
    const float RH = 0.7071067811865476f;   // sqrt(2)/2
    const int tid = threadIdx.x;            // 0..511
    #pragma unroll
    for (int t = 0; t < 4; ++t) {
        const int ls = 3 * t;               // log2(stride): 0,3,6,9
        const int s  = 1 << ls;
        const float theta = fs * 6.283185307179586f / (float)(4096 >> ls);
        float2 a[8];
        #pragma unroll
        for (int m = 0; m < 8; ++m) a[m] = buf[SWZ(tid + m * 512)];
        __syncthreads();
        const int p = tid >> ls;
        const int q = tid & (s - 1);
        float sn, cs;
        __sincosf(theta * (float)p, &sn, &cs);
        const float2 W1 = make_float2(cs, sn);
        const float2 W2 = cmul(W1, W1);
        const float2 W3 = cmul(W2, W1);
        const float2 W4 = cmul(W2, W2);
        const float2 W5 = cmul(W4, W1);
        const float2 W6 = cmul(W4, W2);
        const float2 W7 = cmul(W4, W3);
        // DFT4 of evens (a0,a2,a4,a6) and odds (a1,a3,a5,a7)
        const float2 es = cadd(a[0], a[4]), ed = csub(a[0], a[4]);
        const float2 fs2 = cadd(a[2], a[6]), fd = csub(a[2], a[6]);
        const float2 E0 = cadd(es, fs2);
        const float2 E1 = cadd(ed, cmuli(fd, fs));
        const float2 E2 = csub(es, fs2);
        const float2 E3 = csub(ed, cmuli(fd, fs));
        const float2 os = cadd(a[1], a[5]), od = csub(a[1], a[5]);
        const float2 gs = cadd(a[3], a[7]), gd = csub(a[3], a[7]);
        const float2 O0 = cadd(os, gs);
        const float2 O1 = cadd(od, cmuli(gd, fs));
        const float2 O2 = csub(os, gs);
        const float2 O3 = csub(od, cmuli(gd, fs));
        // T_m = w8^m * O_m  (w8 = e^{i*sign*pi/4})
        const float2 T0 = O0;
        const float2 T1 = make_float2(RH * (O1.x - fs * O1.y), RH * (fs * O1.x + O1.y));
        const float2 T2 = cmuli(O2, fs);
        const float2 T3 = make_float2(RH * (-O3.x - fs * O3.y), RH * (fs * O3.x - O3.y));
        const int o = q + (p << (ls + 3));
        buf[SWZ(o)]         = cadd(E0, T0);
        buf[SWZ(o + s)]     = cmul(W1, cadd(E1, T1));
        buf[SWZ(o + 2*s)]   = cmul(W2, cadd(E2, T2));
        buf[SWZ(o + 3*s)]   = cmul(W3, cadd(E3, T3));
        buf[SWZ(o + 4*s)]   = cmul(W4, csub(E0, T0));
        buf[SWZ(o + 5*s)]   = cmul(W5, csub(E1, T1));
        buf[SWZ(o + 6*s)]   = cmul(W6, csub(E2, T2));
        buf[SWZ(o + 7*s)]   = cmul(W7, csub(E3, T3));
        __syncthreads();
    }
}

// ---------------------------------------------------------------------------
// FFT of filter rows, two real rows per block (z = k_{2d} + i*k_{2d+1}).
// Half-spectra extracted via conjugate symmetry; /4096 folded in.
// ---------------------------------------------------------------------------
__global__ __launch_bounds__(512, 4) void kfft_kernel(
    const float* __restrict__ kfilt, float2* __restrict__ Kf)
{
    __shared__ float2 fb[4096];           // 32 KB
    const int d0 = blockIdx.x * 2;
    const float* k0 = kfilt + (size_t)d0 * LL;
    const float* k1 = k0 + LL;
    const float inv = 1.0f / 4096.0f;
    const int tid = threadIdx.x;
    for (int i = tid; i < 2048; i += 512) {
        fb[SWZ(i)]        = make_float2(k0[i] * inv, k1[i] * inv);
        fb[SWZ(i + 2048)] = make_float2(0.f, 0.f);
    }
    __syncthreads();
    fft4096_r8_ip<-1>(fb);
    float2* o0 = Kf + (size_t)d0 * KF_STRIDE;
    float2* o1 = o0 + KF_STRIDE;
    for (int k = tid; k <= 2048; k += 512) {
        const float2 z1 = fb[SWZ(k)];
        const float2 z2 = fb[SWZ((4096 - k) & 4095)];
        o0[k] = make_float2(0.5f * (z1.x + z2.x), 0.5f * (z1.y - z2.y));
        o1[k] = make_float2(0.5f * (z1.y + z2.y), 0.5f * (z2.x - z1.x));
    }
}

// ---------------------------------------------------------------------------
// Long conv, two real rows per block: z = v1 + i*v2, filter k is REAL.
// vio layout (D, B, L): row r = d*B + b. Block blk handles rows 2blk, 2blk+1
// (same d = blk>>1, adjacent b). In place + bias.
// ---------------------------------------------------------------------------
__global__ __launch_bounds__(512, 4) void fftconv_kernel(
    float* __restrict__ vio, const float2* __restrict__ Kf,
    const float* __restrict__ fbias)
{
    __shared__ float2 fb[4096];           // 32 KB
    const int blk = blockIdx.x;          // [0, 2048)
    const int d   = blk >> 1;
    float* v1 = vio + (size_t)(2 * blk) * LL;
    float* v2 = v1 + LL;
    const int tid = threadIdx.x;
    for (int i = tid; i < 2048; i += 512) {
        fb[SWZ(i)]        = make_float2(v1[i], v2[i]);
        fb[SWZ(i + 2048)] = make_float2(0.f, 0.f);
    }
    __syncthreads();
    fft4096_r8_ip<-1>(fb);
    const float2* kf = Kf + (size_t)d * KF_STRIDE;
    for (int i = tid; i < 4096; i += 512) {
        float2 k;
        if (i <= 2048) k = kf[i];
        else { const float2 t = kf[4096 - i]; k = make_float2(t.x, -t.y); }
        fb[SWZ(i)] = cmul(fb[SWZ(i)], k);
    }
    __syncthreads();
    fft4096_r8_ip<1>(fb);
    const float bias = fbias[d];
    for (int i = tid; i < 2048; i += 512) {
        const float2 zy = fb[SWZ(i)];
        v1[i] = zy.x + bias * v1[i];
        v2[i] = zy.y + bias * v2[i];
    }
}

// ---------------------------------------------------------------------------
// gated_bf16(B,L,D) = bf16( y(D,B,L) * x0t(D,B,L) )  -- LDS 32x32 transpose
// ---------------------------------------------------------------------------
__global__ __launch_bounds__(256) void gate_transpose_kernel(
    const float* __restrict__ y, const bf16_t* __restrict__ x0t,
    bf16_t* __restrict__ g)
{
    __shared__ float tile[32][33];
    const int b  = blockIdx.z;
    const int l0 = blockIdx.x * 32;
    const int d0 = blockIdx.y * 32;
    const int tx  = threadIdx.x & 31;
    const int tyb = threadIdx.x >> 5;    // 0..7
    #pragma unroll
    for (int i = 0; i < 4; ++i) {
        const int dy = tyb + i * 8;
        const size_t src = ((size_t)(d0 + dy) * BB + b) * LL + l0 + tx;
        tile[dy][tx] = y[src] * (float)x0t[src];
    }
    __syncthreads();
    #pragma unroll
    for (int i = 0; i < 4; ++i) {
        const int ly = tyb + i * 8;
        g[((size_t)(b * LL + l0 + ly)) * DD + d0 + tx] = (bf16_t)tile[tx][ly];
    }
}

// ---------------------------------------------------------------------------
// Launch
// ---------------------------------------------------------------------------
extern "C" void kernel_launch(void* const* d_in, const int* in_sizes, int n_in,
                              void* d_out, int out_size, void* d_ws, size_t ws_size,
                              hipStream_t stream)
{
    (void)in_sizes; (void)n_in; (void)out_size; (void)ws_size;
    const float* x   = (const float*)d_in[0];
    const float* nw0 = (const float*)d_in[1];
    const float* ipw = (const float*)d_in[2];
    const float* ipb = (const float*)d_in[3];
    const float* sfw = (const float*)d_in[4];
    const float* sfb = (const float*)d_in[5];
    const float* w1  = (const float*)d_in[6];
    const float* b1  = (const float*)d_in[7];
    const float* f1  = (const float*)d_in[8];
    const float* w2  = (const float*)d_in[9];
    const float* b2  = (const float*)d_in[10];
    const float* f2  = (const float*)d_in[11];
    const float* w3  = (const float*)d_in[12];
    const float* fbv = (const float*)d_in[13];
    const float* opw = (const float*)d_in[14];
    const float* opb = (const float*)d_in[15];
    const float* nw1 = (const float*)d_in[16];
    const float* fw1 = (const float*)d_in[17];
    const float* fb1 = (const float*)d_in[18];
    const float* fw2 = (const float*)d_in[19];
    const float* fb2 = (const float*)d_in[20];
    float* out = (float*)d_out;

    float* ws = (float*)d_ws;
    // Region 0: utb (3D, M) bf16 = 25,165,824 bf16 = 12,582,912 f. After
    // shortfilter consumes utb, the region holds:
    //   gatedb (8M bf16 @ +0), h (8M f @ +4194304)   -- both written later.
    bf16_t* utb    = (bf16_t*)ws;
    bf16_t* gatedb = (bf16_t*)ws;                       // 8,388,608 bf16
    float*  h      = ws + 4194304;                      // 8,388,608 f
    bf16_t* midb   = (bf16_t*)(ws + 12582912);          // 16,777,216 bf16
    bf16_t* xnb    = (bf16_t*)(ws + 25165824);          // 8M bf16 (also hn later)
    bf16_t* x0tb   = (bf16_t*)(ws + 29360128);          // 8,388,608 bf16 (D,B,L)
    float*  vio    = ws + 37748736;                     // 8,388,608 f (D,B,L)
    float*  kfilt  = ws + 46137344;                     // 2,097,152 f
    float2* Kf     = (float2*)(ws + 48234496);          // 1024 x KF_STRIDE cplx
    bf16_t* ipwb   = (bf16_t*)(ws + 52445184);          // 3,145,728 bf16
    bf16_t* opwb   = ipwb + 3145728;                    // 1,048,576 bf16
    bf16_t* fw1b   = opwb + 1048576;                    // 2,097,152 bf16
    bf16_t* fw2b   = fw1b + 2097152;                    // 2,097,152 bf16
    float*  h2t    = ws + 56639488;                     // (64, L) = 131,072 f
    // total: 56,770,560 f = 227.1 MB

    // 0. weight casts (single launch, region-dispatched)
    cast_all_kernel<<<8192, 256, 0, stream>>>(ipw, opw, fw1, fw2,
                                              ipwb, opwb, fw1b, fw2b);
    // 1. implicit filter: MLP phase (h2t), modulation phase (kfilt), FFT (Kf)
    filtermlp_kernel<<<LL/256, 256, 0, stream>>>(w1, b1, f1, w2, b2, f2, h2t);
    filtermod_kernel<<<dim3(LL/256, DD/32), 256, 0, stream>>>(w3, h2t, kfilt);
    kfft_kernel<<<DD/2, 512, 0, stream>>>(kfilt, Kf);
    // 2. xn = bf16(rmsnorm(x, norm_in_w))
    rmsnorm_bf16_kernel<<<MM, 256, 0, stream>>>(x, nw0, xnb);
    // 3. u_t = in_proj_w @ xn^T + b (transposed output, bf16)
    gemm_mfma_kernel<0, true, true><<<dim3(MM/128, 3072/128), 256, 0, stream>>>(
        ipwb, xnb, ipb, nullptr, nullptr, utb, 3*DD, MM, DD);
    // 4. short filter -> x0t (D,B,L) bf16, vin (D,B,L) fp32
    shortfilter_kernel<<<DD, 256, 0, stream>>>(utb, sfw, sfb, x0tb, vio);
    // 5. vio <- causal_conv(vio, k) + filter_bias * vio   (2 rows per block)
    fftconv_kernel<<<BB*DD/2, 512, 0, stream>>>(vio, Kf, fbv);
    // 6. gated_bf16(B,L,D) = y * x0
    gate_transpose_kernel<<<dim3(LL/32, DD/32, BB), 256, 0, stream>>>(vio, x0tb, gatedb);
    // 7. h = gated @ out_proj_w^T + b + x   (M=8192, N=1024, K=1024)
    gemm_mfma_kernel<1, false><<<dim3(DD/128, MM/128), 256, 0, stream>>>(
        gatedb, opwb, opb, x, h, nullptr, MM, DD, DD);
    // 8. hn = bf16(rmsnorm(h, norm_w))
    rmsnorm_bf16_kernel<<<MM, 256, 0, stream>>>(h, nw1, xnb);
    // 9. mid = bf16(gelu(hn @ ffn_w1^T + b))  (M=8192, N=2048, K=1024)
    gemm_mfma_kernel<2, true><<<dim3(2*DD/128, MM/128), 256, 0, stream>>>(
        xnb, fw1b, fb1, nullptr, nullptr, midb, MM, 2*DD, DD);
    // 10. out = mid @ ffn_w2^T + b + h      (M=8192, N=1024, K=2048)
    gemm_mfma_kernel<1, false><<<dim3(DD/128, MM/128), 256, 0, stream>>>(
        midb, fw2b, fb2, h, out, nullptr, MM, DD, 2*DD);
}